// Round 1
// baseline (4559.904 us; speedup 1.0000x reference)
//
#include <hip/hip_runtime.h>
#include <hip/hip_bf16.h>

// ---------- helpers ----------
__device__ __forceinline__ unsigned fenc(float f) {
    unsigned u = __float_as_uint(f);
    return (u & 0x80000000u) ? ~u : (u | 0x80000000u);
}
__device__ __forceinline__ float fdec(unsigned e) {
    unsigned u = (e & 0x80000000u) ? (e & 0x7fffffffu) : ~e;
    return __uint_as_float(u);
}
__device__ __forceinline__ float leaky02(float a) { return a > 0.0f ? a : 0.2f * a; }

// ---------- layer 1: x[N,128] @ W1[128,64] -> xh1[N,64] ----------
__global__ __launch_bounds__(256) void gemm1_kernel(const float* __restrict__ x,
                                                    const float* __restrict__ W,
                                                    float* __restrict__ xh, int N) {
    __shared__ float ws[128 * 64];
    __shared__ float xs[64 * 132];   // pad 128->132 to break bank aliasing
    int tid = threadIdx.x;
    for (int i = tid; i < 128 * 64; i += 256) ws[i] = W[i];
    int row0 = blockIdx.x * 64;
    for (int i = tid; i < 64 * 32; i += 256) {
        int r = i >> 5, c4 = i & 31;
        int row = row0 + r;
        float4 v = make_float4(0.f, 0.f, 0.f, 0.f);
        if (row < N) v = ((const float4*)x)[row * 32 + c4];
        float* p = &xs[r * 132 + c4 * 4];
        p[0] = v.x; p[1] = v.y; p[2] = v.z; p[3] = v.w;
    }
    __syncthreads();
    int tc = tid & 15, tr = tid >> 4;
    float acc[4][4] = {};
    for (int k = 0; k < 128; ++k) {
        float a[4], b[4];
#pragma unroll
        for (int r = 0; r < 4; ++r) a[r] = xs[(tr * 4 + r) * 132 + k];
#pragma unroll
        for (int c = 0; c < 4; ++c) b[c] = ws[k * 64 + tc * 4 + c];
#pragma unroll
        for (int r = 0; r < 4; ++r)
#pragma unroll
            for (int c = 0; c < 4; ++c) acc[r][c] += a[r] * b[c];
    }
#pragma unroll
    for (int r = 0; r < 4; ++r) {
        int row = row0 + tr * 4 + r;
        if (row < N) {
            float4 v = make_float4(acc[r][0], acc[r][1], acc[r][2], acc[r][3]);
            ((float4*)xh)[row * 16 + tc] = v;
        }
    }
}

// ---------- per-node attention scalars, layer 1 (H=8, C=8) ----------
__global__ __launch_bounds__(256) void att1_kernel(const float* __restrict__ xh,
                                                   const float* __restrict__ as_w,
                                                   const float* __restrict__ ad_w,
                                                   float* __restrict__ asrc,
                                                   float* __restrict__ adst, int N) {
    int idx = blockIdx.x * 256 + threadIdx.x;   // over N*8
    if (idx >= N * 8) return;
    int h = idx & 7;
    float4 v0 = ((const float4*)xh)[idx * 2];
    float4 v1 = ((const float4*)xh)[idx * 2 + 1];
    float4 s0 = ((const float4*)as_w)[h * 2];
    float4 s1 = ((const float4*)as_w)[h * 2 + 1];
    float4 d0 = ((const float4*)ad_w)[h * 2];
    float4 d1 = ((const float4*)ad_w)[h * 2 + 1];
    float s = v0.x * s0.x + v0.y * s0.y + v0.z * s0.z + v0.w * s0.w +
              v1.x * s1.x + v1.y * s1.y + v1.z * s1.z + v1.w * s1.w;
    float d = v0.x * d0.x + v0.y * d0.y + v0.z * d0.z + v0.w * d0.w +
              v1.x * d1.x + v1.y * d1.y + v1.z * d1.z + v1.w * d1.w;
    asrc[idx] = s;
    adst[idx] = d;
}

// ---------- layer 1 segment max ----------
__global__ __launch_bounds__(256) void amax1_kernel(const int* __restrict__ ei,
                                                    const float* __restrict__ asrc,
                                                    const float* __restrict__ adst,
                                                    unsigned* __restrict__ amax,
                                                    int E, int Etot) {
    int e = blockIdx.x * 256 + threadIdx.x;
    if (e >= Etot) return;
    int src, dst;
    if (e < E) { src = ei[e]; dst = ei[E + e]; } else { src = dst = e - E; }
    float4 s0 = ((const float4*)asrc)[src * 2], s1 = ((const float4*)asrc)[src * 2 + 1];
    float4 d0 = ((const float4*)adst)[dst * 2], d1 = ((const float4*)adst)[dst * 2 + 1];
    float sv[8] = {s0.x, s0.y, s0.z, s0.w, s1.x, s1.y, s1.z, s1.w};
    float dv[8] = {d0.x, d0.y, d0.z, d0.w, d1.x, d1.y, d1.z, d1.w};
#pragma unroll
    for (int h = 0; h < 8; ++h) {
        float a = leaky02(sv[h] + dv[h]);
        atomicMax(&amax[dst * 8 + h], fenc(a));
    }
}

// ---------- layer 1 denom ----------
__global__ __launch_bounds__(256) void denom1_kernel(const int* __restrict__ ei,
                                                     const float* __restrict__ asrc,
                                                     const float* __restrict__ adst,
                                                     const unsigned* __restrict__ amax,
                                                     float* __restrict__ denom,
                                                     int E, int Etot) {
    int e = blockIdx.x * 256 + threadIdx.x;
    if (e >= Etot) return;
    int src, dst;
    if (e < E) { src = ei[e]; dst = ei[E + e]; } else { src = dst = e - E; }
    float4 s0 = ((const float4*)asrc)[src * 2], s1 = ((const float4*)asrc)[src * 2 + 1];
    float4 d0 = ((const float4*)adst)[dst * 2], d1 = ((const float4*)adst)[dst * 2 + 1];
    uint4 m0 = ((const uint4*)amax)[dst * 2], m1 = ((const uint4*)amax)[dst * 2 + 1];
    float sv[8] = {s0.x, s0.y, s0.z, s0.w, s1.x, s1.y, s1.z, s1.w};
    float dv[8] = {d0.x, d0.y, d0.z, d0.w, d1.x, d1.y, d1.z, d1.w};
    unsigned mv[8] = {m0.x, m0.y, m0.z, m0.w, m1.x, m1.y, m1.z, m1.w};
#pragma unroll
    for (int h = 0; h < 8; ++h) {
        float a = leaky02(sv[h] + dv[h]);
        float ex = expf(a - fdec(mv[h]));
        atomicAdd(&denom[dst * 8 + h], ex);
    }
}

// ---------- layer 1 messages: h1[dst] += xh1[src]*alpha ----------
__global__ __launch_bounds__(256) void msg1_kernel(const int* __restrict__ ei,
                                                   const float* __restrict__ asrc,
                                                   const float* __restrict__ adst,
                                                   const unsigned* __restrict__ amax,
                                                   const float* __restrict__ denom,
                                                   const float* __restrict__ xh,
                                                   float* __restrict__ out,
                                                   int E, int Etot) {
    int idx = blockIdx.x * 256 + threadIdx.x;   // over Etot*8
    if (idx >= Etot * 8) return;
    int e = idx >> 3, h = idx & 7;
    int src, dst;
    if (e < E) { src = ei[e]; dst = ei[E + e]; } else { src = dst = e - E; }
    float a = leaky02(asrc[src * 8 + h] + adst[dst * 8 + h]);
    float m = fdec(amax[dst * 8 + h]);
    float w = expf(a - m) / (denom[dst * 8 + h] + 1e-16f);
    float4 x0 = ((const float4*)xh)[src * 16 + h * 2];
    float4 x1 = ((const float4*)xh)[src * 16 + h * 2 + 1];
    float* op = out + dst * 64 + h * 8;
    atomicAdd(op + 0, x0.x * w);
    atomicAdd(op + 1, x0.y * w);
    atomicAdd(op + 2, x0.z * w);
    atomicAdd(op + 3, x0.w * w);
    atomicAdd(op + 4, x1.x * w);
    atomicAdd(op + 5, x1.y * w);
    atomicAdd(op + 6, x1.z * w);
    atomicAdd(op + 7, x1.w * w);
}

// ---------- bias + ELU (in place on h1) ----------
__global__ __launch_bounds__(256) void bias_elu_kernel(float* __restrict__ h,
                                                       const float* __restrict__ b, int N) {
    int idx = blockIdx.x * 256 + threadIdx.x;   // over N*64
    if (idx >= N * 64) return;
    float v = h[idx] + b[idx & 63];
    h[idx] = v > 0.0f ? v : expm1f(v);
}

// ---------- layer 2 GEMM + attention scalars (H=1, C=8) ----------
__global__ __launch_bounds__(256) void gemm2_kernel(const float* __restrict__ h,
                                                    const float* __restrict__ W2,
                                                    const float* __restrict__ a2s,
                                                    const float* __restrict__ a2d,
                                                    float* __restrict__ xh2,
                                                    float* __restrict__ asrc2,
                                                    float* __restrict__ adst2, int N) {
    __shared__ float hs[32][65];
    __shared__ float w2s[64 * 8];
    __shared__ float xs[32][8];
    int tid = threadIdx.x;
    for (int i = tid; i < 512; i += 256) w2s[i] = W2[i];
    int row0 = blockIdx.x * 32;
    for (int i = tid; i < 512; i += 256) {
        int r = i >> 4, c4 = i & 15;
        int row = row0 + r;
        float4 v = make_float4(0.f, 0.f, 0.f, 0.f);
        if (row < N) v = ((const float4*)h)[row * 16 + c4];
        float* p = &hs[r][c4 * 4];
        p[0] = v.x; p[1] = v.y; p[2] = v.z; p[3] = v.w;
    }
    __syncthreads();
    int r = tid >> 3, c = tid & 7;
    float acc = 0.f;
#pragma unroll 8
    for (int k = 0; k < 64; ++k) acc += hs[r][k] * w2s[k * 8 + c];
    int row = row0 + r;
    if (row < N) xh2[row * 8 + c] = acc;
    xs[r][c] = acc;
    __syncthreads();
    if (tid < 32 && row0 + tid < N) {
        float s = 0.f, d = 0.f;
#pragma unroll
        for (int cc = 0; cc < 8; ++cc) {
            s += xs[tid][cc] * a2s[cc];
            d += xs[tid][cc] * a2d[cc];
        }
        asrc2[row0 + tid] = s;
        adst2[row0 + tid] = d;
    }
}

// ---------- layer 2 segment max ----------
__global__ __launch_bounds__(256) void amax2_kernel(const int* __restrict__ ei,
                                                    const float* __restrict__ asrc,
                                                    const float* __restrict__ adst,
                                                    unsigned* __restrict__ amax,
                                                    int E, int Etot) {
    int e = blockIdx.x * 256 + threadIdx.x;
    if (e >= Etot) return;
    int src, dst;
    if (e < E) { src = ei[e]; dst = ei[E + e]; } else { src = dst = e - E; }
    float a = leaky02(asrc[src] + adst[dst]);
    atomicMax(&amax[dst], fenc(a));
}

// ---------- layer 2 denom ----------
__global__ __launch_bounds__(256) void denom2_kernel(const int* __restrict__ ei,
                                                     const float* __restrict__ asrc,
                                                     const float* __restrict__ adst,
                                                     const unsigned* __restrict__ amax,
                                                     float* __restrict__ denom,
                                                     int E, int Etot) {
    int e = blockIdx.x * 256 + threadIdx.x;
    if (e >= Etot) return;
    int src, dst;
    if (e < E) { src = ei[e]; dst = ei[E + e]; } else { src = dst = e - E; }
    float a = leaky02(asrc[src] + adst[dst]);
    atomicAdd(&denom[dst], expf(a - fdec(amax[dst])));
}

// ---------- layer 2 messages ----------
__global__ __launch_bounds__(256) void msg2_kernel(const int* __restrict__ ei,
                                                   const float* __restrict__ asrc,
                                                   const float* __restrict__ adst,
                                                   const unsigned* __restrict__ amax,
                                                   const float* __restrict__ denom,
                                                   const float* __restrict__ xh2,
                                                   float* __restrict__ out2,
                                                   int E, int Etot) {
    int idx = blockIdx.x * 256 + threadIdx.x;   // over Etot*8
    if (idx >= Etot * 8) return;
    int e = idx >> 3, c = idx & 7;
    int src, dst;
    if (e < E) { src = ei[e]; dst = ei[E + e]; } else { src = dst = e - E; }
    float a = leaky02(asrc[src] + adst[dst]);
    float w = expf(a - fdec(amax[dst])) / (denom[dst] + 1e-16f);
    atomicAdd(&out2[dst * 8 + c], xh2[src * 8 + c] * w);
}

// ---------- mean pool (stage 1: per-block LDS reduce + global atomics) ----------
__global__ __launch_bounds__(256) void pool_kernel(const float* __restrict__ out2,
                                                   const float* __restrict__ b2,
                                                   const int* __restrict__ batch,
                                                   float* __restrict__ pool,
                                                   float* __restrict__ cnt, int N, int B) {
    __shared__ float ps[64 * 8];
    __shared__ float cs[64];
    int tid = threadIdx.x;
    for (int i = tid; i < 512; i += 256) ps[i] = 0.f;
    if (tid < 64) cs[tid] = 0.f;
    __syncthreads();
    int idx = blockIdx.x * 256 + tid;   // over N*8
    if (idx < N * 8) {
        int n = idx >> 3, c = idx & 7;
        int b = batch[n];
        float v = out2[idx] + b2[c];
        atomicAdd(&ps[b * 8 + c], v);
        if (c == 0) atomicAdd(&cs[b], 1.0f);
    }
    __syncthreads();
    for (int i = tid; i < 512; i += 256)
        if (ps[i] != 0.f) atomicAdd(&pool[i], ps[i]);
    if (tid < 64 && cs[tid] != 0.f) atomicAdd(&cnt[tid], cs[tid]);
}

// ---------- final divide ----------
__global__ __launch_bounds__(256) void final_kernel(const float* __restrict__ pool,
                                                    const float* __restrict__ cnt,
                                                    float* __restrict__ out, int B) {
    int idx = blockIdx.x * 256 + threadIdx.x;
    if (idx >= B * 8) return;
    out[idx] = pool[idx] / fmaxf(cnt[idx >> 3], 1.0f);
}

extern "C" void kernel_launch(void* const* d_in, const int* in_sizes, int n_in,
                              void* d_out, int out_size, void* d_ws, size_t ws_size,
                              hipStream_t stream) {
    const float* x   = (const float*)d_in[0];
    const int*   ei  = (const int*)d_in[1];
    const int*   bat = (const int*)d_in[2];
    const float* W1  = (const float*)d_in[3];
    const float* a1s = (const float*)d_in[4];
    const float* a1d = (const float*)d_in[5];
    const float* b1  = (const float*)d_in[6];
    const float* W2  = (const float*)d_in[7];
    const float* a2s = (const float*)d_in[8];
    const float* a2d = (const float*)d_in[9];
    const float* b2  = (const float*)d_in[10];
    float* out = (float*)d_out;

    const int N = in_sizes[0] / 128;
    const int E = in_sizes[1] / 2;
    const int B = out_size / 8;
    const int Etot = E + N;

    // workspace partition (floats)
    float* ws = (float*)d_ws;
    float* xh1   = ws;                       // N*64
    float* asrc1 = xh1 + (size_t)N * 64;     // N*8
    float* adst1 = asrc1 + (size_t)N * 8;    // N*8
    float* xh2   = adst1 + (size_t)N * 8;    // N*8
    float* asrc2 = xh2 + (size_t)N * 8;      // N
    float* adst2 = asrc2 + (size_t)N;        // N
    float* zstart = adst2 + (size_t)N;       // ---- zero-init region ----
    unsigned* amax1 = (unsigned*)zstart;     // N*8
    float* denom1 = zstart + (size_t)N * 8;  // N*8
    float* h1     = denom1 + (size_t)N * 8;  // N*64
    unsigned* amax2 = (unsigned*)(h1 + (size_t)N * 64);  // N
    float* denom2 = (float*)amax2 + (size_t)N;           // N
    float* out2   = denom2 + (size_t)N;      // N*8
    float* pool   = out2 + (size_t)N * 8;    // B*8
    float* cnt    = pool + (size_t)B * 8;    // B
    size_t zbytes = (size_t)((cnt + B) - zstart) * sizeof(float);
    hipMemsetAsync(zstart, 0, zbytes, stream);

    dim3 blk(256);
    // layer 1
    gemm1_kernel<<<dim3((N + 63) / 64), blk, 0, stream>>>(x, W1, xh1, N);
    att1_kernel<<<dim3((N * 8 + 255) / 256), blk, 0, stream>>>(xh1, a1s, a1d, asrc1, adst1, N);
    amax1_kernel<<<dim3((Etot + 255) / 256), blk, 0, stream>>>(ei, asrc1, adst1, amax1, E, Etot);
    denom1_kernel<<<dim3((Etot + 255) / 256), blk, 0, stream>>>(ei, asrc1, adst1, amax1, denom1, E, Etot);
    msg1_kernel<<<dim3((Etot * 8 + 255) / 256), blk, 0, stream>>>(ei, asrc1, adst1, amax1, denom1, xh1, h1, E, Etot);
    bias_elu_kernel<<<dim3((N * 64 + 255) / 256), blk, 0, stream>>>(h1, b1, N);
    // layer 2
    gemm2_kernel<<<dim3((N + 31) / 32), blk, 0, stream>>>(h1, W2, a2s, a2d, xh2, asrc2, adst2, N);
    amax2_kernel<<<dim3((Etot + 255) / 256), blk, 0, stream>>>(ei, asrc2, adst2, amax2, E, Etot);
    denom2_kernel<<<dim3((Etot + 255) / 256), blk, 0, stream>>>(ei, asrc2, adst2, amax2, denom2, E, Etot);
    msg2_kernel<<<dim3((Etot * 8 + 255) / 256), blk, 0, stream>>>(ei, asrc2, adst2, amax2, denom2, xh2, out2, E, Etot);
    // pool
    pool_kernel<<<dim3((N * 8 + 255) / 256), blk, 0, stream>>>(out2, b2, bat, pool, cnt, N, B);
    final_kernel<<<dim3((B * 8 + 255) / 256), blk, 0, stream>>>(pool, cnt, out, B);
}

// Round 2
// 487.853 us; speedup vs baseline: 9.3469x; 9.3469x over previous
//
#include <hip/hip_runtime.h>
#include <hip/hip_bf16.h>

__device__ __forceinline__ float leaky02(float a) { return a > 0.0f ? a : 0.2f * a; }

// ---------- layer 1: x[N,128] @ W1[128,64] -> xh1[N,64] ----------
__global__ __launch_bounds__(256) void gemm1_kernel(const float* __restrict__ x,
                                                    const float* __restrict__ W,
                                                    float* __restrict__ xh, int N) {
    __shared__ float ws[128 * 64];
    __shared__ float xs[64 * 132];
    int tid = threadIdx.x;
    for (int i = tid; i < 128 * 64; i += 256) ws[i] = W[i];
    int row0 = blockIdx.x * 64;
    for (int i = tid; i < 64 * 32; i += 256) {
        int r = i >> 5, c4 = i & 31;
        int row = row0 + r;
        float4 v = make_float4(0.f, 0.f, 0.f, 0.f);
        if (row < N) v = ((const float4*)x)[row * 32 + c4];
        float* p = &xs[r * 132 + c4 * 4];
        p[0] = v.x; p[1] = v.y; p[2] = v.z; p[3] = v.w;
    }
    __syncthreads();
    int tc = tid & 15, tr = tid >> 4;
    float acc[4][4] = {};
    for (int k = 0; k < 128; ++k) {
        float a[4], b[4];
#pragma unroll
        for (int r = 0; r < 4; ++r) a[r] = xs[(tr * 4 + r) * 132 + k];
#pragma unroll
        for (int c = 0; c < 4; ++c) b[c] = ws[k * 64 + tc * 4 + c];
#pragma unroll
        for (int r = 0; r < 4; ++r)
#pragma unroll
            for (int c = 0; c < 4; ++c) acc[r][c] += a[r] * b[c];
    }
#pragma unroll
    for (int r = 0; r < 4; ++r) {
        int row = row0 + tr * 4 + r;
        if (row < N) {
            float4 v = make_float4(acc[r][0], acc[r][1], acc[r][2], acc[r][3]);
            ((float4*)xh)[row * 16 + tc] = v;
        }
    }
}

// ---------- per-node attention scalars, layer 1 (H=8, C=8) ----------
__global__ __launch_bounds__(256) void att1_kernel(const float* __restrict__ xh,
                                                   const float* __restrict__ as_w,
                                                   const float* __restrict__ ad_w,
                                                   float* __restrict__ asrc,
                                                   float* __restrict__ adst, int N) {
    int idx = blockIdx.x * 256 + threadIdx.x;   // over N*8
    if (idx >= N * 8) return;
    int h = idx & 7;
    float4 v0 = ((const float4*)xh)[idx * 2];
    float4 v1 = ((const float4*)xh)[idx * 2 + 1];
    float4 s0 = ((const float4*)as_w)[h * 2];
    float4 s1 = ((const float4*)as_w)[h * 2 + 1];
    float4 d0 = ((const float4*)ad_w)[h * 2];
    float4 d1 = ((const float4*)ad_w)[h * 2 + 1];
    float s = v0.x * s0.x + v0.y * s0.y + v0.z * s0.z + v0.w * s0.w +
              v1.x * s1.x + v1.y * s1.y + v1.z * s1.z + v1.w * s1.w;
    float d = v0.x * d0.x + v0.y * d0.y + v0.z * d0.z + v0.w * d0.w +
              v1.x * d1.x + v1.y * d1.y + v1.z * d1.z + v1.w * d1.w;
    asrc[idx] = s;
    adst[idx] = d;
}

// ---------- CSR build: histogram over dst ----------
__global__ __launch_bounds__(256) void hist_kernel(const int* __restrict__ ei,
                                                   int* __restrict__ deg, int E, int Etot) {
    int e = blockIdx.x * 256 + threadIdx.x;
    if (e >= Etot) return;
    int dst = (e < E) ? ei[E + e] : (e - E);
    atomicAdd(&deg[dst], 1);
}

// ---------- CSR build: block-level exclusive scan (1024 elems / block) ----------
__global__ __launch_bounds__(256) void scan1_kernel(const int* __restrict__ deg,
                                                    int* __restrict__ rowptr,
                                                    int* __restrict__ bsum, int N) {
    __shared__ int sh[256];
    int t = threadIdx.x;
    int base = blockIdx.x * 1024 + t * 4;
    int v[4]; int s = 0;
#pragma unroll
    for (int i = 0; i < 4; ++i) { v[i] = (base + i < N) ? deg[base + i] : 0; s += v[i]; }
    sh[t] = s;
    __syncthreads();
    for (int off = 1; off < 256; off <<= 1) {
        int x = (t >= off) ? sh[t - off] : 0;
        __syncthreads();
        sh[t] += x;
        __syncthreads();
    }
    if (t == 255) bsum[blockIdx.x] = sh[255];
    int run = (t == 0) ? 0 : sh[t - 1];
#pragma unroll
    for (int i = 0; i < 4; ++i) {
        if (base + i < N) rowptr[base + i] = run;
        run += v[i];
    }
}

__global__ __launch_bounds__(1024) void scan2_kernel(const int* __restrict__ bsum,
                                                     int* __restrict__ boffs, int nb) {
    __shared__ int sh[1024];
    int t = threadIdx.x;
    sh[t] = (t < nb) ? bsum[t] : 0;
    __syncthreads();
    for (int off = 1; off < 1024; off <<= 1) {
        int x = (t >= off) ? sh[t - off] : 0;
        __syncthreads();
        sh[t] += x;
        __syncthreads();
    }
    if (t < nb) boffs[t] = (t == 0) ? 0 : sh[t - 1];
}

__global__ __launch_bounds__(256) void scan3_kernel(int* __restrict__ rowptr,
                                                    const int* __restrict__ boffs, int N) {
    int i = blockIdx.x * 256 + threadIdx.x;
    if (i < N) rowptr[i] += boffs[i >> 10];
}

// ---------- CSR build: scatter src ids into dst buckets ----------
__global__ __launch_bounds__(256) void scatter_kernel(const int* __restrict__ ei,
                                                      const int* __restrict__ rowptr,
                                                      int* __restrict__ cnt2,
                                                      int* __restrict__ esrc, int E, int Etot) {
    int e = blockIdx.x * 256 + threadIdx.x;
    if (e >= Etot) return;
    int src, dst;
    if (e < E) { src = ei[e]; dst = ei[E + e]; } else { src = dst = e - E; }
    int pos = rowptr[dst] + atomicAdd(&cnt2[dst], 1);
    esrc[pos] = src;
}

// ---------- layer 1 gather: one wave per node, online softmax, fused bias+ELU ----------
__global__ __launch_bounds__(256) void msg1_csr_kernel(const int* __restrict__ rowptr,
                                                       const int* __restrict__ deg,
                                                       const int* __restrict__ esrc,
                                                       const float* __restrict__ asrc,
                                                       const float* __restrict__ adst,
                                                       const float* __restrict__ xh,
                                                       const float* __restrict__ b1,
                                                       float* __restrict__ h1, int N) {
    int node = blockIdx.x * 4 + (threadIdx.x >> 6);
    if (node >= N) return;
    int lane = threadIdx.x & 63;
    int h = lane >> 3;
    float adh = adst[node * 8 + h];
    int start = rowptr[node], len = deg[node];
    float m = -INFINITY, d = 0.f, acc = 0.f;
    for (int k = 0; k < len; ++k) {
        int s = esrc[start + k];
        float xv = xh[s * 64 + lane];
        float a = leaky02(asrc[s * 8 + h] + adh);
        float mn = fmaxf(m, a);
        float scale = expf(m - mn);
        float p = expf(a - mn);
        d = d * scale + p;
        acc = acc * scale + p * xv;
        m = mn;
    }
    float v = acc / (d + 1e-16f) + b1[lane];
    h1[node * 64 + lane] = v > 0.f ? v : expm1f(v);
}

// ---------- layer 2 GEMM + attention scalars (H=1, C=8) ----------
__global__ __launch_bounds__(256) void gemm2_kernel(const float* __restrict__ h,
                                                    const float* __restrict__ W2,
                                                    const float* __restrict__ a2s,
                                                    const float* __restrict__ a2d,
                                                    float* __restrict__ xh2,
                                                    float* __restrict__ asrc2,
                                                    float* __restrict__ adst2, int N) {
    __shared__ float hs[32][65];
    __shared__ float w2s[64 * 8];
    __shared__ float xs[32][8];
    int tid = threadIdx.x;
    for (int i = tid; i < 512; i += 256) w2s[i] = W2[i];
    int row0 = blockIdx.x * 32;
    for (int i = tid; i < 512; i += 256) {
        int r = i >> 4, c4 = i & 15;
        int row = row0 + r;
        float4 v = make_float4(0.f, 0.f, 0.f, 0.f);
        if (row < N) v = ((const float4*)h)[row * 16 + c4];
        float* p = &hs[r][c4 * 4];
        p[0] = v.x; p[1] = v.y; p[2] = v.z; p[3] = v.w;
    }
    __syncthreads();
    int r = tid >> 3, c = tid & 7;
    float acc = 0.f;
#pragma unroll 8
    for (int k = 0; k < 64; ++k) acc += hs[r][k] * w2s[k * 8 + c];
    int row = row0 + r;
    if (row < N) xh2[row * 8 + c] = acc;
    xs[r][c] = acc;
    __syncthreads();
    if (tid < 32 && row0 + tid < N) {
        float s = 0.f, d = 0.f;
#pragma unroll
        for (int cc = 0; cc < 8; ++cc) {
            s += xs[tid][cc] * a2s[cc];
            d += xs[tid][cc] * a2d[cc];
        }
        asrc2[row0 + tid] = s;
        adst2[row0 + tid] = d;
    }
}

// ---------- layer 2 gather: 8 lanes per node, online softmax, fused bias ----------
__global__ __launch_bounds__(256) void msg2_csr_kernel(const int* __restrict__ rowptr,
                                                       const int* __restrict__ deg,
                                                       const int* __restrict__ esrc,
                                                       const float* __restrict__ asrc2,
                                                       const float* __restrict__ adst2,
                                                       const float* __restrict__ xh2,
                                                       const float* __restrict__ b2,
                                                       float* __restrict__ out2, int N) {
    int node = blockIdx.x * 32 + (threadIdx.x >> 3);
    if (node >= N) return;
    int c = threadIdx.x & 7;
    float adh = adst2[node];
    int start = rowptr[node], len = deg[node];
    float m = -INFINITY, d = 0.f, acc = 0.f;
    for (int k = 0; k < len; ++k) {
        int s = esrc[start + k];
        float xv = xh2[s * 8 + c];
        float a = leaky02(asrc2[s] + adh);
        float mn = fmaxf(m, a);
        float scale = expf(m - mn);
        float p = expf(a - mn);
        d = d * scale + p;
        acc = acc * scale + p * xv;
        m = mn;
    }
    out2[node * 8 + c] = acc / (d + 1e-16f) + b2[c];
}

// ---------- mean pool (per-block LDS reduce + global atomics) ----------
__global__ __launch_bounds__(256) void pool_kernel(const float* __restrict__ out2,
                                                   const int* __restrict__ batch,
                                                   float* __restrict__ pool,
                                                   float* __restrict__ cnt, int N, int B) {
    __shared__ float ps[64 * 8];
    __shared__ float cs[64];
    int tid = threadIdx.x;
    for (int i = tid; i < 512; i += 256) ps[i] = 0.f;
    if (tid < 64) cs[tid] = 0.f;
    __syncthreads();
    int idx = blockIdx.x * 256 + tid;   // over N*8
    if (idx < N * 8) {
        int n = idx >> 3, c = idx & 7;
        int b = batch[n];
        atomicAdd(&ps[b * 8 + c], out2[idx]);
        if (c == 0) atomicAdd(&cs[b], 1.0f);
    }
    __syncthreads();
    for (int i = tid; i < 512; i += 256)
        if (ps[i] != 0.f) atomicAdd(&pool[i], ps[i]);
    if (tid < 64 && cs[tid] != 0.f) atomicAdd(&cnt[tid], cs[tid]);
}

__global__ __launch_bounds__(256) void final_kernel(const float* __restrict__ pool,
                                                    const float* __restrict__ cnt,
                                                    float* __restrict__ out, int B) {
    int idx = blockIdx.x * 256 + threadIdx.x;
    if (idx >= B * 8) return;
    out[idx] = pool[idx] / fmaxf(cnt[idx >> 3], 1.0f);
}

extern "C" void kernel_launch(void* const* d_in, const int* in_sizes, int n_in,
                              void* d_out, int out_size, void* d_ws, size_t ws_size,
                              hipStream_t stream) {
    const float* x   = (const float*)d_in[0];
    const int*   ei  = (const int*)d_in[1];
    const int*   bat = (const int*)d_in[2];
    const float* W1  = (const float*)d_in[3];
    const float* a1s = (const float*)d_in[4];
    const float* a1d = (const float*)d_in[5];
    const float* b1  = (const float*)d_in[6];
    const float* W2  = (const float*)d_in[7];
    const float* a2s = (const float*)d_in[8];
    const float* a2d = (const float*)d_in[9];
    const float* b2  = (const float*)d_in[10];
    float* out = (float*)d_out;

    const int N = in_sizes[0] / 128;
    const int E = in_sizes[1] / 2;
    const int B = out_size / 8;
    const int Etot = E + N;
    const int nb = (N + 1023) / 1024;   // scan blocks (<=1024)

    // ---- workspace layout (all 4-byte elems) ----
    float* ws = (float*)d_ws;
    float* xh1    = ws;                                   // 64N (reused for layer-2 bufs)
    float* asrc1  = xh1 + (size_t)N * 64;                 // 8N
    float* adst1  = asrc1 + (size_t)N * 8;                // 8N
    float* h1     = adst1 + (size_t)N * 8;                // 64N
    int*   rowptr = (int*)(h1 + (size_t)N * 64);          // N (+pad)
    int*   esrc   = rowptr + (size_t)N + 8;               // Etot
    int*   bsum   = esrc + (size_t)Etot;                  // 1024
    int*   boffs  = bsum + 1024;                          // 1024
    // ---- zero-init region ----
    int*   deg    = boffs + 1024;                         // N
    int*   cnt2   = deg + (size_t)N;                      // N
    float* pool   = (float*)(cnt2 + (size_t)N);           // 8B
    float* cnt    = pool + (size_t)B * 8;                 // B
    size_t zbytes = ((size_t)2 * N + 9 * (size_t)B) * 4;
    hipMemsetAsync(deg, 0, zbytes, stream);
    // layer-2 buffers alias xh1's region (xh1 dead after msg1)
    float* xh2    = xh1;                                  // 8N
    float* asrc2  = xh1 + (size_t)N * 8;                  // N
    float* adst2  = xh1 + (size_t)N * 9;                  // N
    float* out2   = xh1 + (size_t)N * 10;                 // 8N

    dim3 blk(256);
    // layer-1 features + attention scalars
    gemm1_kernel<<<dim3((N + 63) / 64), blk, 0, stream>>>(x, W1, xh1, N);
    att1_kernel<<<dim3((N * 8 + 255) / 256), blk, 0, stream>>>(xh1, a1s, a1d, asrc1, adst1, N);
    // CSR build (by dst)
    hist_kernel<<<dim3((Etot + 255) / 256), blk, 0, stream>>>(ei, deg, E, Etot);
    scan1_kernel<<<dim3(nb), blk, 0, stream>>>(deg, rowptr, bsum, N);
    scan2_kernel<<<dim3(1), dim3(1024), 0, stream>>>(bsum, boffs, nb);
    scan3_kernel<<<dim3((N + 255) / 256), blk, 0, stream>>>(rowptr, boffs, N);
    scatter_kernel<<<dim3((Etot + 255) / 256), blk, 0, stream>>>(ei, rowptr, cnt2, esrc, E, Etot);
    // layer-1 aggregate (softmax + messages + bias + ELU fused)
    msg1_csr_kernel<<<dim3((N + 3) / 4), blk, 0, stream>>>(rowptr, deg, esrc, asrc1, adst1, xh1, b1, h1, N);
    // layer 2
    gemm2_kernel<<<dim3((N + 31) / 32), blk, 0, stream>>>(h1, W2, a2s, a2d, xh2, asrc2, adst2, N);
    msg2_csr_kernel<<<dim3((N + 31) / 32), blk, 0, stream>>>(rowptr, deg, esrc, asrc2, adst2, xh2, b2, out2, N);
    // pool
    pool_kernel<<<dim3((N * 8 + 255) / 256), blk, 0, stream>>>(out2, bat, pool, cnt, N, B);
    final_kernel<<<dim3((B * 8 + 255) / 256), blk, 0, stream>>>(pool, cnt, out, B);
}

// Round 3
// 360.045 us; speedup vs baseline: 12.6648x; 1.3550x over previous
//
#include <hip/hip_runtime.h>
#include <hip/hip_bf16.h>

__device__ __forceinline__ float leaky02(float a) { return fmaxf(a, 0.2f * a); }

// ---------- layer 1: x[N,128] @ W1[128,64] -> xh1[N,64], fused att scalars ----------
__global__ __launch_bounds__(256) void gemm1_att_kernel(const float* __restrict__ x,
                                                        const float* __restrict__ W,
                                                        const float* __restrict__ a1s,
                                                        const float* __restrict__ a1d,
                                                        float* __restrict__ xh,
                                                        float* __restrict__ asrc,
                                                        float* __restrict__ adst, int N) {
    __shared__ float ws[128 * 64];
    __shared__ float xs[64 * 132];
    int tid = threadIdx.x;
    for (int i = tid; i < 128 * 64; i += 256) ws[i] = W[i];
    int row0 = blockIdx.x * 64;
    for (int i = tid; i < 64 * 32; i += 256) {
        int r = i >> 5, c4 = i & 31;
        int row = row0 + r;
        float4 v = make_float4(0.f, 0.f, 0.f, 0.f);
        if (row < N) v = ((const float4*)x)[row * 32 + c4];
        float* p = &xs[r * 132 + c4 * 4];
        p[0] = v.x; p[1] = v.y; p[2] = v.z; p[3] = v.w;
    }
    __syncthreads();
    int tc = tid & 15, tr = tid >> 4;
    float acc[4][4] = {};
    for (int k = 0; k < 128; ++k) {
        float a[4], b[4];
#pragma unroll
        for (int r = 0; r < 4; ++r) a[r] = xs[(tr * 4 + r) * 132 + k];
#pragma unroll
        for (int c = 0; c < 4; ++c) b[c] = ws[k * 64 + tc * 4 + c];
#pragma unroll
        for (int r = 0; r < 4; ++r)
#pragma unroll
            for (int c = 0; c < 4; ++c) acc[r][c] += a[r] * b[c];
    }
#pragma unroll
    for (int r = 0; r < 4; ++r) {
        int row = row0 + tr * 4 + r;
        if (row < N) {
            float4 v = make_float4(acc[r][0], acc[r][1], acc[r][2], acc[r][3]);
            ((float4*)xh)[row * 16 + tc] = v;
        }
    }
    // fused attention scalars: features tc*4..tc*4+3 all lie in head tc>>1
    float4 sv = ((const float4*)a1s)[tc];
    float4 dv = ((const float4*)a1d)[tc];
    int head = tc >> 1;
#pragma unroll
    for (int r = 0; r < 4; ++r) {
        float sp = acc[r][0] * sv.x + acc[r][1] * sv.y + acc[r][2] * sv.z + acc[r][3] * sv.w;
        float dp = acc[r][0] * dv.x + acc[r][1] * dv.y + acc[r][2] * dv.z + acc[r][3] * dv.w;
        sp += __shfl_xor(sp, 1);
        dp += __shfl_xor(dp, 1);
        int row = row0 + tr * 4 + r;
        if (!(tc & 1) && row < N) {
            asrc[row * 8 + head] = sp;
            adst[row * 8 + head] = dp;
        }
    }
}

// ---------- CSR build ----------
__global__ __launch_bounds__(256) void hist_kernel(const int* __restrict__ ei,
                                                   int* __restrict__ deg, int E, int Etot) {
    int e = blockIdx.x * 256 + threadIdx.x;
    if (e >= Etot) return;
    int dst = (e < E) ? ei[E + e] : (e - E);
    atomicAdd(&deg[dst], 1);
}

__global__ __launch_bounds__(256) void scan1_kernel(const int* __restrict__ deg,
                                                    int* __restrict__ rowptr,
                                                    int* __restrict__ bsum, int N) {
    __shared__ int sh[256];
    int t = threadIdx.x;
    int base = blockIdx.x * 1024 + t * 4;
    int v[4]; int s = 0;
#pragma unroll
    for (int i = 0; i < 4; ++i) { v[i] = (base + i < N) ? deg[base + i] : 0; s += v[i]; }
    sh[t] = s;
    __syncthreads();
    for (int off = 1; off < 256; off <<= 1) {
        int x = (t >= off) ? sh[t - off] : 0;
        __syncthreads();
        sh[t] += x;
        __syncthreads();
    }
    if (t == 255) bsum[blockIdx.x] = sh[255];
    int run = (t == 0) ? 0 : sh[t - 1];
#pragma unroll
    for (int i = 0; i < 4; ++i) {
        if (base + i < N) rowptr[base + i] = run;
        run += v[i];
    }
}

__global__ __launch_bounds__(1024) void scan2_kernel(const int* __restrict__ bsum,
                                                     int* __restrict__ boffs, int nb) {
    __shared__ int sh[1024];
    int t = threadIdx.x;
    sh[t] = (t < nb) ? bsum[t] : 0;
    __syncthreads();
    for (int off = 1; off < 1024; off <<= 1) {
        int x = (t >= off) ? sh[t - off] : 0;
        __syncthreads();
        sh[t] += x;
        __syncthreads();
    }
    if (t < nb) boffs[t] = (t == 0) ? 0 : sh[t - 1];
}

__global__ __launch_bounds__(256) void scan3_kernel(int* __restrict__ rowptr,
                                                    const int* __restrict__ boffs, int N) {
    int i = blockIdx.x * 256 + threadIdx.x;
    if (i < N) rowptr[i] += boffs[i >> 10];
}

__global__ __launch_bounds__(256) void scatter_kernel(const int* __restrict__ ei,
                                                      const int* __restrict__ rowptr,
                                                      int* __restrict__ cnt2,
                                                      int* __restrict__ esrc, int E, int Etot) {
    int e = blockIdx.x * 256 + threadIdx.x;
    if (e >= Etot) return;
    int src, dst;
    if (e < E) { src = ei[e]; dst = ei[E + e]; } else { src = dst = e - E; }
    int pos = rowptr[dst] + atomicAdd(&cnt2[dst], 1);
    esrc[pos] = src;
}

// ---------- fused: layer-1 aggregate + bias + ELU + layer-2 GEMM + att2 scalars ----------
// one wave per node; lane = slot*8 + h  (slot = edge sub-slot, h = head)
__global__ __launch_bounds__(256) void agg1_fused_kernel(const int* __restrict__ rowptr,
                                                         const int* __restrict__ deg,
                                                         const int* __restrict__ esrc,
                                                         const float* __restrict__ asrc,
                                                         const float* __restrict__ adst,
                                                         const float* __restrict__ xh,
                                                         const float* __restrict__ b1,
                                                         const float* __restrict__ W2,
                                                         const float* __restrict__ a2s,
                                                         const float* __restrict__ a2d,
                                                         float* __restrict__ xh2,
                                                         float* __restrict__ asrc2,
                                                         float* __restrict__ adst2, int N) {
    int node = blockIdx.x * 4 + (threadIdx.x >> 6);
    if (node >= N) return;
    int lane = threadIdx.x & 63;
    int slot = lane >> 3, h = lane & 7;
    float adh = adst[node * 8 + h];
    int start = rowptr[node], len = deg[node];
    float d = 0.f;
    float acc[8] = {};
    for (int kb = 0; kb < len; kb += 8) {
        int k = kb + slot;
        if (k < len) {
            int s = esrc[start + k];
            float a = leaky02(asrc[s * 8 + h] + adh);
            float p = __expf(a);
            const float4* xp = (const float4*)(xh + ((size_t)s << 6) + (h << 3));
            float4 v0 = xp[0], v1 = xp[1];
            d += p;
            acc[0] += p * v0.x; acc[1] += p * v0.y; acc[2] += p * v0.z; acc[3] += p * v0.w;
            acc[4] += p * v1.x; acc[5] += p * v1.y; acc[6] += p * v1.z; acc[7] += p * v1.w;
        }
    }
    // reduce over the 8 slot-lanes (lane bits 3..5)
#pragma unroll
    for (int off = 8; off < 64; off <<= 1) {
        d += __shfl_xor(d, off);
#pragma unroll
        for (int c = 0; c < 8; ++c) acc[c] += __shfl_xor(acc[c], off);
    }
    // this lane owns feature f = h*8 + slot  (channel 'slot' of head 'h')
    float inv = 1.0f / (d + 1e-16f);
    float hv = acc[0];
#pragma unroll
    for (int c = 1; c < 8; ++c) hv = (slot == c) ? acc[c] : hv;
    int f = h * 8 + slot;
    hv = hv * inv + b1[f];
    hv = hv > 0.f ? hv : __expf(hv) - 1.0f;          // ELU
    // fused layer-2 GEMM: xh2[node][c2] = sum_f hv(f) * W2[f][c2]
    const float4* wp = (const float4*)(W2 + f * 8);
    float4 w0 = wp[0], w1 = wp[1];
    float q[8] = {hv * w0.x, hv * w0.y, hv * w0.z, hv * w0.w,
                  hv * w1.x, hv * w1.y, hv * w1.z, hv * w1.w};
#pragma unroll
    for (int off = 1; off < 64; off <<= 1)
#pragma unroll
        for (int c = 0; c < 8; ++c) q[c] += __shfl_xor(q[c], off);
    // every lane now has xh2[node][0..7]
    if (lane < 8) {
        float v = q[0];
#pragma unroll
        for (int c = 1; c < 8; ++c) v = (lane == c) ? q[c] : v;
        xh2[node * 8 + lane] = v;
    }
    if (lane == 0) {
        float s2 = 0.f, d2 = 0.f;
#pragma unroll
        for (int c = 0; c < 8; ++c) { s2 += q[c] * a2s[c]; d2 += q[c] * a2d[c]; }
        asrc2[node] = s2;
        adst2[node] = d2;
    }
}

// ---------- layer-2 aggregate: 8 lanes per node (lane = edge slot) ----------
__global__ __launch_bounds__(256) void agg2_kernel(const int* __restrict__ rowptr,
                                                   const int* __restrict__ deg,
                                                   const int* __restrict__ esrc,
                                                   const float* __restrict__ asrc2,
                                                   const float* __restrict__ adst2,
                                                   const float* __restrict__ xh2,
                                                   const float* __restrict__ b2,
                                                   float* __restrict__ out2, int N) {
    int node = blockIdx.x * 32 + (threadIdx.x >> 3);
    if (node >= N) return;
    int slot = threadIdx.x & 7;
    float adh = adst2[node];
    int start = rowptr[node], len = deg[node];
    float d = 0.f;
    float acc[8] = {};
    for (int kb = 0; kb < len; kb += 8) {
        int k = kb + slot;
        if (k < len) {
            int s = esrc[start + k];
            float a = leaky02(asrc2[s] + adh);
            float p = __expf(a);
            const float4* xp = (const float4*)(xh2 + ((size_t)s << 3));
            float4 v0 = xp[0], v1 = xp[1];
            d += p;
            acc[0] += p * v0.x; acc[1] += p * v0.y; acc[2] += p * v0.z; acc[3] += p * v0.w;
            acc[4] += p * v1.x; acc[5] += p * v1.y; acc[6] += p * v1.z; acc[7] += p * v1.w;
        }
    }
#pragma unroll
    for (int off = 1; off < 8; off <<= 1) {
        d += __shfl_xor(d, off);
#pragma unroll
        for (int c = 0; c < 8; ++c) acc[c] += __shfl_xor(acc[c], off);
    }
    float v = acc[0];
#pragma unroll
    for (int c = 1; c < 8; ++c) v = (slot == c) ? acc[c] : v;
    out2[node * 8 + slot] = v / (d + 1e-16f) + b2[slot];
}

// ---------- mean pool ----------
__global__ __launch_bounds__(256) void pool_kernel(const float* __restrict__ out2,
                                                   const int* __restrict__ batch,
                                                   float* __restrict__ pool,
                                                   float* __restrict__ cnt, int N, int B) {
    __shared__ float ps[64 * 8];
    __shared__ float cs[64];
    int tid = threadIdx.x;
    for (int i = tid; i < 512; i += 256) ps[i] = 0.f;
    if (tid < 64) cs[tid] = 0.f;
    __syncthreads();
    int idx = blockIdx.x * 256 + tid;   // over N*8
    if (idx < N * 8) {
        int n = idx >> 3, c = idx & 7;
        int b = batch[n];
        atomicAdd(&ps[b * 8 + c], out2[idx]);
        if (c == 0) atomicAdd(&cs[b], 1.0f);
    }
    __syncthreads();
    for (int i = tid; i < 512; i += 256)
        if (ps[i] != 0.f) atomicAdd(&pool[i], ps[i]);
    if (tid < 64 && cs[tid] != 0.f) atomicAdd(&cnt[tid], cs[tid]);
}

__global__ __launch_bounds__(256) void final_kernel(const float* __restrict__ pool,
                                                    const float* __restrict__ cnt,
                                                    float* __restrict__ out, int B) {
    int idx = blockIdx.x * 256 + threadIdx.x;
    if (idx >= B * 8) return;
    out[idx] = pool[idx] / fmaxf(cnt[idx >> 3], 1.0f);
}

extern "C" void kernel_launch(void* const* d_in, const int* in_sizes, int n_in,
                              void* d_out, int out_size, void* d_ws, size_t ws_size,
                              hipStream_t stream) {
    const float* x   = (const float*)d_in[0];
    const int*   ei  = (const int*)d_in[1];
    const int*   bat = (const int*)d_in[2];
    const float* W1  = (const float*)d_in[3];
    const float* a1s = (const float*)d_in[4];
    const float* a1d = (const float*)d_in[5];
    const float* b1  = (const float*)d_in[6];
    const float* W2  = (const float*)d_in[7];
    const float* a2s = (const float*)d_in[8];
    const float* a2d = (const float*)d_in[9];
    const float* b2  = (const float*)d_in[10];
    float* out = (float*)d_out;

    const int N = in_sizes[0] / 128;
    const int E = in_sizes[1] / 2;
    const int B = out_size / 8;
    const int Etot = E + N;
    const int nb = (N + 1023) / 1024;

    // ---- workspace layout ----
    float* ws = (float*)d_ws;
    float* xh1    = ws;                                   // 64N
    float* asrc1  = xh1 + (size_t)N * 64;                 // 8N
    float* adst1  = asrc1 + (size_t)N * 8;                // 8N
    float* xh2    = adst1 + (size_t)N * 8;                // 8N
    float* asrc2  = xh2 + (size_t)N * 8;                  // N
    float* adst2  = asrc2 + (size_t)N;                    // N
    float* out2   = adst2 + (size_t)N;                    // 8N
    int*   rowptr = (int*)(out2 + (size_t)N * 8);         // N (+pad)
    int*   esrc   = rowptr + (size_t)N + 8;               // Etot
    int*   bsum   = esrc + (size_t)Etot;                  // 1024
    int*   boffs  = bsum + 1024;                          // 1024
    // ---- zero-init region ----
    int*   deg    = boffs + 1024;                         // N
    int*   cnt2   = deg + (size_t)N;                      // N
    float* pool   = (float*)(cnt2 + (size_t)N);           // 8B
    float* cnt    = pool + (size_t)B * 8;                 // B
    size_t zbytes = ((size_t)2 * N + 9 * (size_t)B) * 4;
    hipMemsetAsync(deg, 0, zbytes, stream);

    dim3 blk(256);
    gemm1_att_kernel<<<dim3((N + 63) / 64), blk, 0, stream>>>(x, W1, a1s, a1d, xh1, asrc1, adst1, N);
    hist_kernel<<<dim3((Etot + 255) / 256), blk, 0, stream>>>(ei, deg, E, Etot);
    scan1_kernel<<<dim3(nb), blk, 0, stream>>>(deg, rowptr, bsum, N);
    scan2_kernel<<<dim3(1), dim3(1024), 0, stream>>>(bsum, boffs, nb);
    scan3_kernel<<<dim3((N + 255) / 256), blk, 0, stream>>>(rowptr, boffs, N);
    scatter_kernel<<<dim3((Etot + 255) / 256), blk, 0, stream>>>(ei, rowptr, cnt2, esrc, E, Etot);
    agg1_fused_kernel<<<dim3((N + 3) / 4), blk, 0, stream>>>(rowptr, deg, esrc, asrc1, adst1,
                                                             xh1, b1, W2, a2s, a2d,
                                                             xh2, asrc2, adst2, N);
    agg2_kernel<<<dim3((N + 31) / 32), blk, 0, stream>>>(rowptr, deg, esrc, asrc2, adst2, xh2, b2, out2, N);
    pool_kernel<<<dim3((N * 8 + 255) / 256), blk, 0, stream>>>(out2, bat, pool, cnt, N, B);
    final_kernel<<<dim3((B * 8 + 255) / 256), blk, 0, stream>>>(pool, cnt, out, B);
}

// Round 4
// 324.577 us; speedup vs baseline: 14.0488x; 1.1093x over previous
//
#include <hip/hip_runtime.h>
#include <hip/hip_bf16.h>

__device__ __forceinline__ float leaky02(float a) { return fmaxf(a, 0.2f * a); }

// ---------- layer 1: x[N,128] @ W1[128,64] -> xh1[N,64], fused att scalars + edge histogram ----------
__global__ __launch_bounds__(256) void gemm1_att_hist_kernel(const float* __restrict__ x,
                                                             const float* __restrict__ W,
                                                             const float* __restrict__ a1s,
                                                             const float* __restrict__ a1d,
                                                             const int* __restrict__ ei,
                                                             float* __restrict__ xh,
                                                             float* __restrict__ asrc,
                                                             float* __restrict__ adst,
                                                             int* __restrict__ deg,
                                                             int N, int E, int Etot) {
    __shared__ float ws[128 * 64];
    __shared__ float xs[64 * 132];
    int tid = threadIdx.x;
    for (int i = tid; i < 128 * 64; i += 256) ws[i] = W[i];
    int row0 = blockIdx.x * 64;
    for (int i = tid; i < 64 * 32; i += 256) {
        int r = i >> 5, c4 = i & 31;
        int row = row0 + r;
        float4 v = make_float4(0.f, 0.f, 0.f, 0.f);
        if (row < N) v = ((const float4*)x)[row * 32 + c4];
        float* p = &xs[r * 132 + c4 * 4];
        p[0] = v.x; p[1] = v.y; p[2] = v.z; p[3] = v.w;
    }
    __syncthreads();
    int tc = tid & 15, tr = tid >> 4;
    float acc[4][4] = {};
    for (int k = 0; k < 128; ++k) {
        float a[4], b[4];
#pragma unroll
        for (int r = 0; r < 4; ++r) a[r] = xs[(tr * 4 + r) * 132 + k];
#pragma unroll
        for (int c = 0; c < 4; ++c) b[c] = ws[k * 64 + tc * 4 + c];
#pragma unroll
        for (int r = 0; r < 4; ++r)
#pragma unroll
            for (int c = 0; c < 4; ++c) acc[r][c] += a[r] * b[c];
    }
#pragma unroll
    for (int r = 0; r < 4; ++r) {
        int row = row0 + tr * 4 + r;
        if (row < N) {
            float4 v = make_float4(acc[r][0], acc[r][1], acc[r][2], acc[r][3]);
            ((float4*)xh)[row * 16 + tc] = v;
        }
    }
    // fused attention scalars
    float4 sv = ((const float4*)a1s)[tc];
    float4 dv = ((const float4*)a1d)[tc];
    int head = tc >> 1;
#pragma unroll
    for (int r = 0; r < 4; ++r) {
        float sp = acc[r][0] * sv.x + acc[r][1] * sv.y + acc[r][2] * sv.z + acc[r][3] * sv.w;
        float dp = acc[r][0] * dv.x + acc[r][1] * dv.y + acc[r][2] * dv.z + acc[r][3] * dv.w;
        sp += __shfl_xor(sp, 1);
        dp += __shfl_xor(dp, 1);
        int row = row0 + tr * 4 + r;
        if (!(tc & 1) && row < N) {
            asrc[row * 8 + head] = sp;
            adst[row * 8 + head] = dp;
        }
    }
    // fused degree histogram over this block's slice of edges (fire-and-forget atomics,
    // overlaps other blocks' GEMM compute)
    int nblk = gridDim.x;
    long long per = ((long long)Etot + nblk - 1) / nblk;
    long long e0 = (long long)blockIdx.x * per;
    long long e1 = e0 + per; if (e1 > Etot) e1 = Etot;
    for (long long e = e0 + tid; e < e1; e += 256) {
        int dst = (e < E) ? ei[E + e] : (int)(e - E);
        atomicAdd(&deg[dst], 1);
    }
}

// ---------- CSR build: scans ----------
__global__ __launch_bounds__(256) void scan1_kernel(const int* __restrict__ deg,
                                                    int* __restrict__ rowptr,
                                                    int* __restrict__ bsum, int N) {
    __shared__ int sh[256];
    int t = threadIdx.x;
    int base = blockIdx.x * 1024 + t * 4;
    int v[4]; int s = 0;
#pragma unroll
    for (int i = 0; i < 4; ++i) { v[i] = (base + i < N) ? deg[base + i] : 0; s += v[i]; }
    sh[t] = s;
    __syncthreads();
    for (int off = 1; off < 256; off <<= 1) {
        int x = (t >= off) ? sh[t - off] : 0;
        __syncthreads();
        sh[t] += x;
        __syncthreads();
    }
    if (t == 255) bsum[blockIdx.x] = sh[255];
    int run = (t == 0) ? 0 : sh[t - 1];
#pragma unroll
    for (int i = 0; i < 4; ++i) {
        if (base + i < N) rowptr[base + i] = run;
        run += v[i];
    }
}

__global__ __launch_bounds__(1024) void scan2_kernel(const int* __restrict__ bsum,
                                                     int* __restrict__ boffs, int nb) {
    __shared__ int sh[1024];
    int t = threadIdx.x;
    sh[t] = (t < nb) ? bsum[t] : 0;
    __syncthreads();
    for (int off = 1; off < 1024; off <<= 1) {
        int x = (t >= off) ? sh[t - off] : 0;
        __syncthreads();
        sh[t] += x;
        __syncthreads();
    }
    if (t < nb) boffs[t] = (t == 0) ? 0 : sh[t - 1];
}

__global__ __launch_bounds__(256) void scan3_kernel(int* __restrict__ rowptr,
                                                    int* __restrict__ wptr,
                                                    const int* __restrict__ boffs, int N) {
    int i = blockIdx.x * 256 + threadIdx.x;
    if (i < N) {
        int v = rowptr[i] + boffs[i >> 10];
        rowptr[i] = v;
        wptr[i] = v;
    }
}

// ---------- CSR build: scatter, 4 edges/thread, single fused wptr atomic ----------
__global__ __launch_bounds__(256) void scatter_kernel(const int* __restrict__ ei,
                                                      int* __restrict__ wptr,
                                                      int* __restrict__ esrc, int E, int Etot) {
    int base = (blockIdx.x * 256 + threadIdx.x) * 4;
    int srcs[4], dsts[4], pos[4];
    bool ok[4];
#pragma unroll
    for (int i = 0; i < 4; ++i) {
        int e = base + i;
        ok[i] = e < Etot;
        if (ok[i]) {
            if (e < E) { srcs[i] = ei[e]; dsts[i] = ei[E + e]; }
            else       { srcs[i] = dsts[i] = e - E; }
        }
    }
#pragma unroll
    for (int i = 0; i < 4; ++i)
        if (ok[i]) pos[i] = atomicAdd(&wptr[dsts[i]], 1);
#pragma unroll
    for (int i = 0; i < 4; ++i)
        if (ok[i]) esrc[pos[i]] = srcs[i];
}

// ---------- fused: layer-1 aggregate + bias + ELU + layer-2 GEMM + att2 scalars ----------
// one wave per node; lane = slot*8 + h
__global__ __launch_bounds__(256) void agg1_fused_kernel(const int* __restrict__ rowptr,
                                                         const int* __restrict__ deg,
                                                         const int* __restrict__ esrc,
                                                         const float* __restrict__ asrc,
                                                         const float* __restrict__ adst,
                                                         const float* __restrict__ xh,
                                                         const float* __restrict__ b1,
                                                         const float* __restrict__ W2,
                                                         const float* __restrict__ a2s,
                                                         const float* __restrict__ a2d,
                                                         float* __restrict__ xh2,
                                                         float* __restrict__ asrc2,
                                                         float* __restrict__ adst2, int N) {
    int node = blockIdx.x * 4 + (threadIdx.x >> 6);
    if (node >= N) return;
    int lane = threadIdx.x & 63;
    int slot = lane >> 3, h = lane & 7;
    float adh = adst[node * 8 + h];
    int start = rowptr[node], len = deg[node];
    float d = 0.f;
    float acc[8] = {};
    for (int kb = 0; kb < len; kb += 8) {
        int k = kb + slot;
        if (k < len) {
            int s = esrc[start + k];
            float a = leaky02(asrc[s * 8 + h] + adh);
            float p = __expf(a);
            const float4* xp = (const float4*)(xh + ((size_t)s << 6) + (h << 3));
            float4 v0 = xp[0], v1 = xp[1];
            d += p;
            acc[0] += p * v0.x; acc[1] += p * v0.y; acc[2] += p * v0.z; acc[3] += p * v0.w;
            acc[4] += p * v1.x; acc[5] += p * v1.y; acc[6] += p * v1.z; acc[7] += p * v1.w;
        }
    }
#pragma unroll
    for (int off = 8; off < 64; off <<= 1) {
        d += __shfl_xor(d, off);
#pragma unroll
        for (int c = 0; c < 8; ++c) acc[c] += __shfl_xor(acc[c], off);
    }
    float inv = 1.0f / (d + 1e-16f);
    float hv = acc[0];
#pragma unroll
    for (int c = 1; c < 8; ++c) hv = (slot == c) ? acc[c] : hv;
    int f = h * 8 + slot;
    hv = hv * inv + b1[f];
    hv = hv > 0.f ? hv : __expf(hv) - 1.0f;          // ELU
    const float4* wp = (const float4*)(W2 + f * 8);
    float4 w0 = wp[0], w1 = wp[1];
    float q[8] = {hv * w0.x, hv * w0.y, hv * w0.z, hv * w0.w,
                  hv * w1.x, hv * w1.y, hv * w1.z, hv * w1.w};
#pragma unroll
    for (int off = 1; off < 64; off <<= 1)
#pragma unroll
        for (int c = 0; c < 8; ++c) q[c] += __shfl_xor(q[c], off);
    if (lane < 8) {
        float v = q[0];
#pragma unroll
        for (int c = 1; c < 8; ++c) v = (lane == c) ? q[c] : v;
        xh2[node * 8 + lane] = v;
    }
    if (lane == 0) {
        float s2 = 0.f, d2 = 0.f;
#pragma unroll
        for (int c = 0; c < 8; ++c) { s2 += q[c] * a2s[c]; d2 += q[c] * a2d[c]; }
        asrc2[node] = s2;
        adst2[node] = d2;
    }
}

// ---------- layer-2 aggregate: 8 lanes per node ----------
__global__ __launch_bounds__(256) void agg2_kernel(const int* __restrict__ rowptr,
                                                   const int* __restrict__ deg,
                                                   const int* __restrict__ esrc,
                                                   const float* __restrict__ asrc2,
                                                   const float* __restrict__ adst2,
                                                   const float* __restrict__ xh2,
                                                   const float* __restrict__ b2,
                                                   float* __restrict__ out2, int N) {
    int node = blockIdx.x * 32 + (threadIdx.x >> 3);
    if (node >= N) return;
    int slot = threadIdx.x & 7;
    float adh = adst2[node];
    int start = rowptr[node], len = deg[node];
    float d = 0.f;
    float acc[8] = {};
    for (int kb = 0; kb < len; kb += 8) {
        int k = kb + slot;
        if (k < len) {
            int s = esrc[start + k];
            float a = leaky02(asrc2[s] + adh);
            float p = __expf(a);
            const float4* xp = (const float4*)(xh2 + ((size_t)s << 3));
            float4 v0 = xp[0], v1 = xp[1];
            d += p;
            acc[0] += p * v0.x; acc[1] += p * v0.y; acc[2] += p * v0.z; acc[3] += p * v0.w;
            acc[4] += p * v1.x; acc[5] += p * v1.y; acc[6] += p * v1.z; acc[7] += p * v1.w;
        }
    }
#pragma unroll
    for (int off = 1; off < 8; off <<= 1) {
        d += __shfl_xor(d, off);
#pragma unroll
        for (int c = 0; c < 8; ++c) acc[c] += __shfl_xor(acc[c], off);
    }
    float v = acc[0];
#pragma unroll
    for (int c = 1; c < 8; ++c) v = (slot == c) ? acc[c] : v;
    out2[node * 8 + slot] = v / (d + 1e-16f) + b2[slot];
}

// ---------- mean pool ----------
__global__ __launch_bounds__(256) void pool_kernel(const float* __restrict__ out2,
                                                   const int* __restrict__ batch,
                                                   float* __restrict__ pool,
                                                   float* __restrict__ cnt, int N, int B) {
    __shared__ float ps[64 * 8];
    __shared__ float cs[64];
    int tid = threadIdx.x;
    for (int i = tid; i < 512; i += 256) ps[i] = 0.f;
    if (tid < 64) cs[tid] = 0.f;
    __syncthreads();
    int idx = blockIdx.x * 256 + tid;   // over N*8
    if (idx < N * 8) {
        int n = idx >> 3, c = idx & 7;
        int b = batch[n];
        atomicAdd(&ps[b * 8 + c], out2[idx]);
        if (c == 0) atomicAdd(&cs[b], 1.0f);
    }
    __syncthreads();
    for (int i = tid; i < 512; i += 256)
        if (ps[i] != 0.f) atomicAdd(&pool[i], ps[i]);
    if (tid < 64 && cs[tid] != 0.f) atomicAdd(&cnt[tid], cs[tid]);
}

__global__ __launch_bounds__(256) void final_kernel(const float* __restrict__ pool,
                                                    const float* __restrict__ cnt,
                                                    float* __restrict__ out, int B) {
    int idx = blockIdx.x * 256 + threadIdx.x;
    if (idx >= B * 8) return;
    out[idx] = pool[idx] / fmaxf(cnt[idx >> 3], 1.0f);
}

extern "C" void kernel_launch(void* const* d_in, const int* in_sizes, int n_in,
                              void* d_out, int out_size, void* d_ws, size_t ws_size,
                              hipStream_t stream) {
    const float* x   = (const float*)d_in[0];
    const int*   ei  = (const int*)d_in[1];
    const int*   bat = (const int*)d_in[2];
    const float* W1  = (const float*)d_in[3];
    const float* a1s = (const float*)d_in[4];
    const float* a1d = (const float*)d_in[5];
    const float* b1  = (const float*)d_in[6];
    const float* W2  = (const float*)d_in[7];
    const float* a2s = (const float*)d_in[8];
    const float* a2d = (const float*)d_in[9];
    const float* b2  = (const float*)d_in[10];
    float* out = (float*)d_out;

    const int N = in_sizes[0] / 128;
    const int E = in_sizes[1] / 2;
    const int B = out_size / 8;
    const int Etot = E + N;
    const int nb = (N + 1023) / 1024;

    // ---- workspace layout ----
    float* ws = (float*)d_ws;
    float* xh1    = ws;                                   // 64N
    float* asrc1  = xh1 + (size_t)N * 64;                 // 8N
    float* adst1  = asrc1 + (size_t)N * 8;                // 8N
    float* xh2    = adst1 + (size_t)N * 8;                // 8N
    float* asrc2  = xh2 + (size_t)N * 8;                  // N
    float* adst2  = asrc2 + (size_t)N;                    // N
    float* out2   = adst2 + (size_t)N;                    // 8N
    int*   rowptr = (int*)(out2 + (size_t)N * 8);         // N (+pad)
    int*   wptr   = rowptr + (size_t)N + 8;               // N
    int*   esrc   = wptr + (size_t)N;                     // Etot
    int*   bsum   = esrc + (size_t)Etot;                  // 1024
    int*   boffs  = bsum + 1024;                          // 1024
    // ---- zero-init region ----
    int*   deg    = boffs + 1024;                         // N
    float* pool   = (float*)(deg + (size_t)N);            // 8B
    float* cnt    = pool + (size_t)B * 8;                 // B
    size_t zbytes = ((size_t)N + 9 * (size_t)B) * 4;
    hipMemsetAsync(deg, 0, zbytes, stream);

    dim3 blk(256);
    gemm1_att_hist_kernel<<<dim3((N + 63) / 64), blk, 0, stream>>>(x, W1, a1s, a1d, ei,
                                                                   xh1, asrc1, adst1, deg,
                                                                   N, E, Etot);
    scan1_kernel<<<dim3(nb), blk, 0, stream>>>(deg, rowptr, bsum, N);
    scan2_kernel<<<dim3(1), dim3(1024), 0, stream>>>(bsum, boffs, nb);
    scan3_kernel<<<dim3((N + 255) / 256), blk, 0, stream>>>(rowptr, wptr, boffs, N);
    scatter_kernel<<<dim3((Etot + 1023) / 1024), blk, 0, stream>>>(ei, wptr, esrc, E, Etot);
    agg1_fused_kernel<<<dim3((N + 3) / 4), blk, 0, stream>>>(rowptr, deg, esrc, asrc1, adst1,
                                                             xh1, b1, W2, a2s, a2d,
                                                             xh2, asrc2, adst2, N);
    agg2_kernel<<<dim3((N + 31) / 32), blk, 0, stream>>>(rowptr, deg, esrc, asrc2, adst2, xh2, b2, out2, N);
    pool_kernel<<<dim3((N * 8 + 255) / 256), blk, 0, stream>>>(out2, bat, pool, cnt, N, B);
    final_kernel<<<dim3((B * 8 + 255) / 256), blk, 0, stream>>>(pool, cnt, out, B);
}

// Round 5
// 315.682 us; speedup vs baseline: 14.4446x; 1.0282x over previous
//
#include <hip/hip_runtime.h>
#include <hip/hip_bf16.h>

__device__ __forceinline__ float leaky02(float a) { return fmaxf(a, 0.2f * a); }
__device__ __forceinline__ unsigned short f2bf(float f) {
    __hip_bfloat16 h = __float2bfloat16(f);
    return *(unsigned short*)&h;
}
__device__ __forceinline__ float bflo(unsigned u) { return __uint_as_float(u << 16); }
__device__ __forceinline__ float bfhi(unsigned u) { return __uint_as_float(u & 0xffff0000u); }

// ---------- layer 1: x[N,128] @ W1[128,64] -> xh1(bf16), att scalars, edge histogram ----------
// 32-row tile: LDS = 32KiB (W) + 16.9KiB (x) = 48.9KiB -> 3 blocks/CU
__global__ __launch_bounds__(256) void gemm1_att_hist_kernel(const float* __restrict__ x,
                                                             const float* __restrict__ W,
                                                             const float* __restrict__ a1s,
                                                             const float* __restrict__ a1d,
                                                             const int* __restrict__ ei,
                                                             __hip_bfloat16* __restrict__ xh,
                                                             float* __restrict__ asrc,
                                                             float* __restrict__ adst,
                                                             int* __restrict__ deg,
                                                             int N, int E, int Etot) {
    __shared__ float ws[128 * 64];     // [k][c], same layout as W1
    __shared__ float xs[32][132];
    int tid = threadIdx.x;
    for (int i = tid; i < 2048; i += 256) ((float4*)ws)[i] = ((const float4*)W)[i];
    int row0 = blockIdx.x * 32;
    for (int i = tid; i < 32 * 32; i += 256) {
        int r = i >> 5, c4 = i & 31;
        int row = row0 + r;
        float4 v = make_float4(0.f, 0.f, 0.f, 0.f);
        if (row < N) v = ((const float4*)x)[row * 32 + c4];
        float* p = &xs[r][c4 * 4];
        p[0] = v.x; p[1] = v.y; p[2] = v.z; p[3] = v.w;
    }
    __syncthreads();
    int tc = tid & 15, tr = tid >> 4;      // cols tc*4..+3, rows tr*2, tr*2+1
    float acc[2][4] = {};
#pragma unroll 4
    for (int k = 0; k < 128; ++k) {
        float a0 = xs[tr * 2][k];
        float a1 = xs[tr * 2 + 1][k];
        float4 b = *(const float4*)&ws[k * 64 + tc * 4];
        acc[0][0] += a0 * b.x; acc[0][1] += a0 * b.y; acc[0][2] += a0 * b.z; acc[0][3] += a0 * b.w;
        acc[1][0] += a1 * b.x; acc[1][1] += a1 * b.y; acc[1][2] += a1 * b.z; acc[1][3] += a1 * b.w;
    }
    float4 sv = ((const float4*)a1s)[tc];
    float4 dv = ((const float4*)a1d)[tc];
    int head = tc >> 1;
#pragma unroll
    for (int r = 0; r < 2; ++r) {
        int row = row0 + tr * 2 + r;
        if (row < N) {
            uint2 o;
            o.x = (unsigned)f2bf(acc[r][0]) | ((unsigned)f2bf(acc[r][1]) << 16);
            o.y = (unsigned)f2bf(acc[r][2]) | ((unsigned)f2bf(acc[r][3]) << 16);
            *(uint2*)(xh + (size_t)row * 64 + tc * 4) = o;
        }
        float sp = acc[r][0] * sv.x + acc[r][1] * sv.y + acc[r][2] * sv.z + acc[r][3] * sv.w;
        float dp = acc[r][0] * dv.x + acc[r][1] * dv.y + acc[r][2] * dv.z + acc[r][3] * dv.w;
        sp += __shfl_xor(sp, 1);
        dp += __shfl_xor(dp, 1);
        if (!(tc & 1) && row < N) {
            asrc[row * 8 + head] = sp;
            adst[row * 8 + head] = dp;
        }
    }
    // fused degree histogram (fire-and-forget atomics overlap other blocks' GEMM)
    int nblk = gridDim.x;
    long long per = ((long long)Etot + nblk - 1) / nblk;
    long long e0 = (long long)blockIdx.x * per;
    long long e1 = e0 + per; if (e1 > Etot) e1 = Etot;
    for (long long e = e0 + tid; e < e1; e += 256) {
        int dst = (e < E) ? ei[E + e] : (int)(e - E);
        atomicAdd(&deg[dst], 1);
    }
}

// ---------- CSR scans ----------
__global__ __launch_bounds__(256) void scan1_kernel(const int* __restrict__ deg,
                                                    int* __restrict__ rowptr,
                                                    int* __restrict__ bsum, int N) {
    __shared__ int sh[256];
    int t = threadIdx.x;
    int base = blockIdx.x * 1024 + t * 4;
    int v[4]; int s = 0;
#pragma unroll
    for (int i = 0; i < 4; ++i) { v[i] = (base + i < N) ? deg[base + i] : 0; s += v[i]; }
    sh[t] = s;
    __syncthreads();
    for (int off = 1; off < 256; off <<= 1) {
        int x = (t >= off) ? sh[t - off] : 0;
        __syncthreads();
        sh[t] += x;
        __syncthreads();
    }
    if (t == 255) bsum[blockIdx.x] = sh[255];
    int run = (t == 0) ? 0 : sh[t - 1];
#pragma unroll
    for (int i = 0; i < 4; ++i) {
        if (base + i < N) rowptr[base + i] = run;
        run += v[i];
    }
}

__global__ __launch_bounds__(1024) void scan2_kernel(const int* __restrict__ bsum,
                                                     int* __restrict__ boffs, int nb) {
    __shared__ int sh[1024];
    int t = threadIdx.x;
    sh[t] = (t < nb) ? bsum[t] : 0;
    __syncthreads();
    for (int off = 1; off < 1024; off <<= 1) {
        int x = (t >= off) ? sh[t - off] : 0;
        __syncthreads();
        sh[t] += x;
        __syncthreads();
    }
    if (t < nb) boffs[t] = (t == 0) ? 0 : sh[t - 1];
}

__global__ __launch_bounds__(256) void scan3_kernel(int* __restrict__ rowptr,
                                                    int* __restrict__ wptr,
                                                    const int* __restrict__ boffs, int N) {
    int i = blockIdx.x * 256 + threadIdx.x;
    if (i < N) {
        int v = rowptr[i] + boffs[i >> 10];
        rowptr[i] = v;
        wptr[i] = v;
    }
}

// ---------- scatter: 8 edges/thread, fused wptr atomic ----------
__global__ __launch_bounds__(256) void scatter_kernel(const int* __restrict__ ei,
                                                      int* __restrict__ wptr,
                                                      int* __restrict__ esrc, int E, int Etot) {
    int base = (blockIdx.x * 256 + threadIdx.x) * 8;
    int srcs[8], dsts[8], pos[8];
    bool ok[8];
#pragma unroll
    for (int i = 0; i < 8; ++i) {
        int e = base + i;
        ok[i] = e < Etot;
        if (ok[i]) {
            if (e < E) { srcs[i] = ei[e]; dsts[i] = ei[E + e]; }
            else       { srcs[i] = dsts[i] = e - E; }
        }
    }
#pragma unroll
    for (int i = 0; i < 8; ++i)
        if (ok[i]) pos[i] = atomicAdd(&wptr[dsts[i]], 1);
#pragma unroll
    for (int i = 0; i < 8; ++i)
        if (ok[i]) esrc[pos[i]] = srcs[i];
}

// ---------- fused: layer-1 aggregate + bias + ELU + layer-2 GEMM + att2 scalars ----------
// one wave per node; lane = slot*8 + h
__global__ __launch_bounds__(256) void agg1_fused_kernel(const int* __restrict__ rowptr,
                                                         const int* __restrict__ deg,
                                                         const int* __restrict__ esrc,
                                                         const float* __restrict__ asrc,
                                                         const float* __restrict__ adst,
                                                         const __hip_bfloat16* __restrict__ xh,
                                                         const float* __restrict__ b1,
                                                         const float* __restrict__ W2,
                                                         const float* __restrict__ a2s,
                                                         const float* __restrict__ a2d,
                                                         __hip_bfloat16* __restrict__ xh2,
                                                         float* __restrict__ asrc2,
                                                         float* __restrict__ adst2, int N) {
    int node = blockIdx.x * 4 + (threadIdx.x >> 6);
    if (node >= N) return;
    int lane = threadIdx.x & 63;
    int slot = lane >> 3, h = lane & 7;
    float adh = adst[node * 8 + h];
    int start = rowptr[node], len = deg[node];
    float d = 0.f;
    float acc[8] = {};
    for (int kb = 0; kb < len; kb += 8) {
        int k = kb + slot;
        if (k < len) {
            int s = esrc[start + k];
            float a = leaky02(asrc[s * 8 + h] + adh);
            float p = __expf(a);
            uint4 u = ((const uint4*)(xh + ((size_t)s << 6)))[h];   // 8 bf16 = this head's channels
            d += p;
            acc[0] += p * bflo(u.x); acc[1] += p * bfhi(u.x);
            acc[2] += p * bflo(u.y); acc[3] += p * bfhi(u.y);
            acc[4] += p * bflo(u.z); acc[5] += p * bfhi(u.z);
            acc[6] += p * bflo(u.w); acc[7] += p * bfhi(u.w);
        }
    }
#pragma unroll
    for (int off = 8; off < 64; off <<= 1) {
        d += __shfl_xor(d, off);
#pragma unroll
        for (int c = 0; c < 8; ++c) acc[c] += __shfl_xor(acc[c], off);
    }
    float inv = 1.0f / (d + 1e-16f);
    float hv = acc[0];
#pragma unroll
    for (int c = 1; c < 8; ++c) hv = (slot == c) ? acc[c] : hv;
    int f = h * 8 + slot;
    hv = hv * inv + b1[f];
    hv = hv > 0.f ? hv : __expf(hv) - 1.0f;          // ELU
    const float4* wp = (const float4*)(W2 + f * 8);
    float4 w0 = wp[0], w1 = wp[1];
    float q[8] = {hv * w0.x, hv * w0.y, hv * w0.z, hv * w0.w,
                  hv * w1.x, hv * w1.y, hv * w1.z, hv * w1.w};
#pragma unroll
    for (int off = 1; off < 64; off <<= 1)
#pragma unroll
        for (int c = 0; c < 8; ++c) q[c] += __shfl_xor(q[c], off);
    if (lane == 0) {
        uint4 o;
        o.x = (unsigned)f2bf(q[0]) | ((unsigned)f2bf(q[1]) << 16);
        o.y = (unsigned)f2bf(q[2]) | ((unsigned)f2bf(q[3]) << 16);
        o.z = (unsigned)f2bf(q[4]) | ((unsigned)f2bf(q[5]) << 16);
        o.w = (unsigned)f2bf(q[6]) | ((unsigned)f2bf(q[7]) << 16);
        *(uint4*)(xh2 + (size_t)node * 8) = o;
        float s2 = 0.f, d2 = 0.f;
#pragma unroll
        for (int c = 0; c < 8; ++c) { s2 += q[c] * a2s[c]; d2 += q[c] * a2d[c]; }
        asrc2[node] = s2;
        adst2[node] = d2;
    }
}

// ---------- layer-2 aggregate + bias + fused mean-pool stage ----------
__global__ __launch_bounds__(256) void agg2_pool_kernel(const int* __restrict__ rowptr,
                                                        const int* __restrict__ deg,
                                                        const int* __restrict__ esrc,
                                                        const float* __restrict__ asrc2,
                                                        const float* __restrict__ adst2,
                                                        const __hip_bfloat16* __restrict__ xh2,
                                                        const float* __restrict__ b2,
                                                        const int* __restrict__ batch,
                                                        float* __restrict__ pool,
                                                        float* __restrict__ cnt, int N, int B) {
    __shared__ float ps[64 * 8];
    __shared__ float cs[64];
    int tid = threadIdx.x;
    for (int i = tid; i < 512; i += 256) ps[i] = 0.f;
    if (tid < 64) cs[tid] = 0.f;
    __syncthreads();
    int node = blockIdx.x * 32 + (tid >> 3);
    int slot = tid & 7;
    if (node < N) {
        float adh = adst2[node];
        int start = rowptr[node], len = deg[node];
        float d = 0.f;
        float acc[8] = {};
        for (int kb = 0; kb < len; kb += 8) {
            int k = kb + slot;
            if (k < len) {
                int s = esrc[start + k];
                float a = leaky02(asrc2[s] + adh);
                float p = __expf(a);
                uint4 u = *(const uint4*)(xh2 + ((size_t)s << 3));
                d += p;
                acc[0] += p * bflo(u.x); acc[1] += p * bfhi(u.x);
                acc[2] += p * bflo(u.y); acc[3] += p * bfhi(u.y);
                acc[4] += p * bflo(u.z); acc[5] += p * bfhi(u.z);
                acc[6] += p * bflo(u.w); acc[7] += p * bfhi(u.w);
            }
        }
#pragma unroll
        for (int off = 1; off < 8; off <<= 1) {
            d += __shfl_xor(d, off);
#pragma unroll
            for (int c = 0; c < 8; ++c) acc[c] += __shfl_xor(acc[c], off);
        }
        float v = acc[0];
#pragma unroll
        for (int c = 1; c < 8; ++c) v = (slot == c) ? acc[c] : v;
        v = v / (d + 1e-16f) + b2[slot];
        int b = batch[node];
        atomicAdd(&ps[b * 8 + slot], v);
        if (slot == 0) atomicAdd(&cs[b], 1.0f);
    }
    __syncthreads();
    for (int i = tid; i < 512; i += 256)
        if (ps[i] != 0.f) atomicAdd(&pool[i], ps[i]);
    if (tid < 64 && cs[tid] != 0.f) atomicAdd(&cnt[tid], cs[tid]);
}

__global__ __launch_bounds__(256) void final_kernel(const float* __restrict__ pool,
                                                    const float* __restrict__ cnt,
                                                    float* __restrict__ out, int B) {
    int idx = blockIdx.x * 256 + threadIdx.x;
    if (idx >= B * 8) return;
    out[idx] = pool[idx] / fmaxf(cnt[idx >> 3], 1.0f);
}

extern "C" void kernel_launch(void* const* d_in, const int* in_sizes, int n_in,
                              void* d_out, int out_size, void* d_ws, size_t ws_size,
                              hipStream_t stream) {
    const float* x   = (const float*)d_in[0];
    const int*   ei  = (const int*)d_in[1];
    const int*   bat = (const int*)d_in[2];
    const float* W1  = (const float*)d_in[3];
    const float* a1s = (const float*)d_in[4];
    const float* a1d = (const float*)d_in[5];
    const float* b1  = (const float*)d_in[6];
    const float* W2  = (const float*)d_in[7];
    const float* a2s = (const float*)d_in[8];
    const float* a2d = (const float*)d_in[9];
    const float* b2  = (const float*)d_in[10];
    float* out = (float*)d_out;

    const int N = in_sizes[0] / 128;
    const int E = in_sizes[1] / 2;
    const int B = out_size / 8;
    const int Etot = E + N;
    const int nb = (N + 1023) / 1024;

    // ---- workspace layout (float slots) ----
    float* wsp = (float*)d_ws;
    __hip_bfloat16* xh1 = (__hip_bfloat16*)wsp;           // 64N bf16 = 32N floats
    float* asrc1  = wsp + (size_t)N * 32;                 // 8N
    float* adst1  = asrc1 + (size_t)N * 8;                // 8N
    __hip_bfloat16* xh2 = (__hip_bfloat16*)(adst1 + (size_t)N * 8);  // 8N bf16 = 4N floats
    float* asrc2  = adst1 + (size_t)N * 12;               // N
    float* adst2  = asrc2 + (size_t)N;                    // N
    int*   rowptr = (int*)(adst2 + (size_t)N);            // N (+pad)
    int*   wptr   = rowptr + (size_t)N + 8;               // N
    int*   esrc   = wptr + (size_t)N;                     // Etot
    int*   bsum   = esrc + (size_t)Etot;                  // 1024
    int*   boffs  = bsum + 1024;                          // 1024
    // ---- zero-init region ----
    int*   deg    = boffs + 1024;                         // N
    float* pool   = (float*)(deg + (size_t)N);            // 8B
    float* cnt    = pool + (size_t)B * 8;                 // B
    size_t zbytes = ((size_t)N + 9 * (size_t)B) * 4;
    hipMemsetAsync(deg, 0, zbytes, stream);

    dim3 blk(256);
    gemm1_att_hist_kernel<<<dim3((N + 31) / 32), blk, 0, stream>>>(x, W1, a1s, a1d, ei,
                                                                   xh1, asrc1, adst1, deg,
                                                                   N, E, Etot);
    scan1_kernel<<<dim3(nb), blk, 0, stream>>>(deg, rowptr, bsum, N);
    scan2_kernel<<<dim3(1), dim3(1024), 0, stream>>>(bsum, boffs, nb);
    scan3_kernel<<<dim3((N + 255) / 256), blk, 0, stream>>>(rowptr, wptr, boffs, N);
    scatter_kernel<<<dim3((Etot + 2047) / 2048), blk, 0, stream>>>(ei, wptr, esrc, E, Etot);
    agg1_fused_kernel<<<dim3((N + 3) / 4), blk, 0, stream>>>(rowptr, deg, esrc, asrc1, adst1,
                                                             xh1, b1, W2, a2s, a2d,
                                                             xh2, asrc2, adst2, N);
    agg2_pool_kernel<<<dim3((N + 31) / 32), blk, 0, stream>>>(rowptr, deg, esrc, asrc2, adst2,
                                                              xh2, b2, bat, pool, cnt, N, B);
    final_kernel<<<dim3((B * 8 + 255) / 256), blk, 0, stream>>>(pool, cnt, out, B);
}

// Round 6
// 208.900 us; speedup vs baseline: 21.8282x; 1.5112x over previous
//
#include <hip/hip_runtime.h>
#include <hip/hip_bf16.h>

#define BIN_SHIFT 8                  // 256 nodes per bin
#define BIN_NODES 256
#define BIN_CAP   8192               // >> mean bin load (~4400), 58 sigma safe
#define EPT       32                 // edges per thread in binB

__device__ __forceinline__ float leaky02(float a) { return fmaxf(a, 0.2f * a); }
__device__ __forceinline__ unsigned short f2bf(float f) {
    __hip_bfloat16 h = __float2bfloat16(f);
    return *(unsigned short*)&h;
}
__device__ __forceinline__ float bflo(unsigned u) { return __uint_as_float(u << 16); }
__device__ __forceinline__ float bfhi(unsigned u) { return __uint_as_float(u & 0xffff0000u); }

// ---------- layer 1: x[N,128] @ W1[128,64] -> xh1(bf16) + att scalars ----------
__global__ __launch_bounds__(256) void gemm1_att_kernel(const float* __restrict__ x,
                                                        const float* __restrict__ W,
                                                        const float* __restrict__ a1s,
                                                        const float* __restrict__ a1d,
                                                        __hip_bfloat16* __restrict__ xh,
                                                        float* __restrict__ asrc,
                                                        float* __restrict__ adst, int N) {
    __shared__ float ws[128 * 64];
    __shared__ float xs[32][132];
    int tid = threadIdx.x;
    for (int i = tid; i < 2048; i += 256) ((float4*)ws)[i] = ((const float4*)W)[i];
    int row0 = blockIdx.x * 32;
    for (int i = tid; i < 32 * 32; i += 256) {
        int r = i >> 5, c4 = i & 31;
        int row = row0 + r;
        float4 v = make_float4(0.f, 0.f, 0.f, 0.f);
        if (row < N) v = ((const float4*)x)[row * 32 + c4];
        float* p = &xs[r][c4 * 4];
        p[0] = v.x; p[1] = v.y; p[2] = v.z; p[3] = v.w;
    }
    __syncthreads();
    int tc = tid & 15, tr = tid >> 4;
    float acc[2][4] = {};
#pragma unroll 4
    for (int k = 0; k < 128; ++k) {
        float a0 = xs[tr * 2][k];
        float a1 = xs[tr * 2 + 1][k];
        float4 b = *(const float4*)&ws[k * 64 + tc * 4];
        acc[0][0] += a0 * b.x; acc[0][1] += a0 * b.y; acc[0][2] += a0 * b.z; acc[0][3] += a0 * b.w;
        acc[1][0] += a1 * b.x; acc[1][1] += a1 * b.y; acc[1][2] += a1 * b.z; acc[1][3] += a1 * b.w;
    }
    float4 sv = ((const float4*)a1s)[tc];
    float4 dv = ((const float4*)a1d)[tc];
    int head = tc >> 1;
#pragma unroll
    for (int r = 0; r < 2; ++r) {
        int row = row0 + tr * 2 + r;
        if (row < N) {
            uint2 o;
            o.x = (unsigned)f2bf(acc[r][0]) | ((unsigned)f2bf(acc[r][1]) << 16);
            o.y = (unsigned)f2bf(acc[r][2]) | ((unsigned)f2bf(acc[r][3]) << 16);
            *(uint2*)(xh + (size_t)row * 64 + tc * 4) = o;
        }
        float sp = acc[r][0] * sv.x + acc[r][1] * sv.y + acc[r][2] * sv.z + acc[r][3] * sv.w;
        float dp = acc[r][0] * dv.x + acc[r][1] * dv.y + acc[r][2] * dv.z + acc[r][3] * dv.w;
        sp += __shfl_xor(sp, 1);
        dp += __shfl_xor(dp, 1);
        if (!(tc & 1) && row < N) {
            asrc[row * 8 + head] = sp;
            adst[row * 8 + head] = dp;
        }
    }
}

// ---------- binB: bin edges by dst>>8 into fixed-capacity buckets ----------
// LDS-aggregated counts -> one bulk reservation atomic per (block,bin) -> grouped writes
__global__ __launch_bounds__(256) void binB_kernel(const int* __restrict__ ei,
                                                   int* __restrict__ cur,        // [NB] zeroed
                                                   unsigned* __restrict__ binned, // [NB*BIN_CAP]
                                                   int E, int Etot, int NB) {
    __shared__ int bcnt[512];
    int tid = threadIdx.x;
    for (int i = tid; i < 512; i += 256) bcnt[i] = 0;
    __syncthreads();
    long long base = (long long)blockIdx.x * 256 * EPT;
#pragma unroll 4
    for (int i = 0; i < EPT; ++i) {
        long long e = base + i * 256 + tid;
        if (e < Etot) {
            int dst = (e < E) ? ei[E + e] : (int)(e - E);
            atomicAdd(&bcnt[dst >> BIN_SHIFT], 1);
        }
    }
    __syncthreads();
    // reserve per-bin ranges; bcnt becomes the running write cursor
    for (int b = tid; b < NB; b += 256) {
        int c = bcnt[b];
        bcnt[b] = c ? atomicAdd(&cur[b], c) : 0;
    }
    __syncthreads();
#pragma unroll 4
    for (int i = 0; i < EPT; ++i) {
        long long e = base + i * 256 + tid;
        if (e < Etot) {
            int src, dst;
            if (e < E) { src = ei[e]; dst = ei[E + e]; }
            else       { src = dst = (int)(e - E); }
            int bin = dst >> BIN_SHIFT;
            int p = atomicAdd(&bcnt[bin], 1);
            if (p < BIN_CAP)
                binned[(size_t)bin * BIN_CAP + p] = ((unsigned)(dst & (BIN_NODES - 1)) << 24) | (unsigned)src;
        }
    }
}

// ---------- binC: per-bin -> rowptr + in-bin scatter to esrc (no global atomics) ----------
__global__ __launch_bounds__(256) void binC_kernel(const int* __restrict__ cur,
                                                   const unsigned* __restrict__ binned,
                                                   int* __restrict__ rowptr,   // [N+1]
                                                   int* __restrict__ esrc,     // [Etot]
                                                   int N, int Etot, int NB) {
    int bin = blockIdx.x;
    int tid = threadIdx.x;
    __shared__ int psum[256];
    __shared__ int sc[256];
    __shared__ int ndc[256];
    // base = exclusive prefix of bin totals
    int s = 0;
    for (int i = tid; i < bin; i += 256) s += cur[i];
    psum[tid] = s;
    __syncthreads();
    for (int off = 128; off > 0; off >>= 1) {
        if (tid < off) psum[tid] += psum[tid + off];
        __syncthreads();
    }
    int bbase = psum[0];
    int cnt = cur[bin];
    ndc[tid] = 0;
    __syncthreads();
    const unsigned* bp = binned + (size_t)bin * BIN_CAP;
    for (int i = tid; i < cnt; i += 256)
        atomicAdd(&ndc[bp[i] >> 24], 1);
    __syncthreads();
    int v = ndc[tid];
    sc[tid] = v;
    __syncthreads();
    for (int off = 1; off < 256; off <<= 1) {
        int t = (tid >= off) ? sc[tid - off] : 0;
        __syncthreads();
        sc[tid] += t;
        __syncthreads();
    }
    int excl = sc[tid] - v;
    int node = bin * BIN_NODES + tid;
    if (node < N) rowptr[node] = bbase + excl;
    if (bin == NB - 1 && tid == 0) rowptr[N] = Etot;
    ndc[tid] = excl;          // running in-bin cursor
    __syncthreads();
    for (int i = tid; i < cnt; i += 256) {
        unsigned w = bp[i];
        int p = atomicAdd(&ndc[w >> 24], 1);
        esrc[bbase + p] = (int)(w & 0xFFFFFFu);
    }
}

// ---------- fused: layer-1 aggregate + bias + ELU + layer-2 GEMM + att2 scalars ----------
__global__ __launch_bounds__(256) void agg1_fused_kernel(const int* __restrict__ rowptr,
                                                         const int* __restrict__ esrc,
                                                         const float* __restrict__ asrc,
                                                         const float* __restrict__ adst,
                                                         const __hip_bfloat16* __restrict__ xh,
                                                         const float* __restrict__ b1,
                                                         const float* __restrict__ W2,
                                                         const float* __restrict__ a2s,
                                                         const float* __restrict__ a2d,
                                                         __hip_bfloat16* __restrict__ xh2,
                                                         float* __restrict__ asrc2,
                                                         float* __restrict__ adst2, int N) {
    int node = blockIdx.x * 4 + (threadIdx.x >> 6);
    if (node >= N) return;
    int lane = threadIdx.x & 63;
    int slot = lane >> 3, h = lane & 7;
    float adh = adst[node * 8 + h];
    int start = rowptr[node], len = rowptr[node + 1] - start;
    float d = 0.f;
    float acc[8] = {};
    for (int kb = 0; kb < len; kb += 8) {
        int k = kb + slot;
        if (k < len) {
            int s = esrc[start + k];
            float a = leaky02(asrc[s * 8 + h] + adh);
            float p = __expf(a);
            uint4 u = ((const uint4*)(xh + ((size_t)s << 6)))[h];
            d += p;
            acc[0] += p * bflo(u.x); acc[1] += p * bfhi(u.x);
            acc[2] += p * bflo(u.y); acc[3] += p * bfhi(u.y);
            acc[4] += p * bflo(u.z); acc[5] += p * bfhi(u.z);
            acc[6] += p * bflo(u.w); acc[7] += p * bfhi(u.w);
        }
    }
#pragma unroll
    for (int off = 8; off < 64; off <<= 1) {
        d += __shfl_xor(d, off);
#pragma unroll
        for (int c = 0; c < 8; ++c) acc[c] += __shfl_xor(acc[c], off);
    }
    float inv = 1.0f / (d + 1e-16f);
    float hv = acc[0];
#pragma unroll
    for (int c = 1; c < 8; ++c) hv = (slot == c) ? acc[c] : hv;
    int f = h * 8 + slot;
    hv = hv * inv + b1[f];
    hv = hv > 0.f ? hv : __expf(hv) - 1.0f;          // ELU
    const float4* wp = (const float4*)(W2 + f * 8);
    float4 w0 = wp[0], w1 = wp[1];
    float q[8] = {hv * w0.x, hv * w0.y, hv * w0.z, hv * w0.w,
                  hv * w1.x, hv * w1.y, hv * w1.z, hv * w1.w};
#pragma unroll
    for (int off = 1; off < 64; off <<= 1)
#pragma unroll
        for (int c = 0; c < 8; ++c) q[c] += __shfl_xor(q[c], off);
    if (lane == 0) {
        uint4 o;
        o.x = (unsigned)f2bf(q[0]) | ((unsigned)f2bf(q[1]) << 16);
        o.y = (unsigned)f2bf(q[2]) | ((unsigned)f2bf(q[3]) << 16);
        o.z = (unsigned)f2bf(q[4]) | ((unsigned)f2bf(q[5]) << 16);
        o.w = (unsigned)f2bf(q[6]) | ((unsigned)f2bf(q[7]) << 16);
        *(uint4*)(xh2 + (size_t)node * 8) = o;
        float s2 = 0.f, d2 = 0.f;
#pragma unroll
        for (int c = 0; c < 8; ++c) { s2 += q[c] * a2s[c]; d2 += q[c] * a2d[c]; }
        asrc2[node] = s2;
        adst2[node] = d2;
    }
}

// ---------- layer-2 aggregate + bias + fused mean-pool stage ----------
__global__ __launch_bounds__(256) void agg2_pool_kernel(const int* __restrict__ rowptr,
                                                        const int* __restrict__ esrc,
                                                        const float* __restrict__ asrc2,
                                                        const float* __restrict__ adst2,
                                                        const __hip_bfloat16* __restrict__ xh2,
                                                        const float* __restrict__ b2,
                                                        const int* __restrict__ batch,
                                                        float* __restrict__ pool,
                                                        float* __restrict__ cnt, int N, int B) {
    __shared__ float ps[64 * 8];
    __shared__ float cs[64];
    int tid = threadIdx.x;
    for (int i = tid; i < 512; i += 256) ps[i] = 0.f;
    if (tid < 64) cs[tid] = 0.f;
    __syncthreads();
    int node = blockIdx.x * 32 + (tid >> 3);
    int slot = tid & 7;
    if (node < N) {
        float adh = adst2[node];
        int start = rowptr[node], len = rowptr[node + 1] - start;
        float d = 0.f;
        float acc[8] = {};
        for (int kb = 0; kb < len; kb += 8) {
            int k = kb + slot;
            if (k < len) {
                int s = esrc[start + k];
                float a = leaky02(asrc2[s] + adh);
                float p = __expf(a);
                uint4 u = *(const uint4*)(xh2 + ((size_t)s << 3));
                d += p;
                acc[0] += p * bflo(u.x); acc[1] += p * bfhi(u.x);
                acc[2] += p * bflo(u.y); acc[3] += p * bfhi(u.y);
                acc[4] += p * bflo(u.z); acc[5] += p * bfhi(u.z);
                acc[6] += p * bflo(u.w); acc[7] += p * bfhi(u.w);
            }
        }
#pragma unroll
        for (int off = 1; off < 8; off <<= 1) {
            d += __shfl_xor(d, off);
#pragma unroll
            for (int c = 0; c < 8; ++c) acc[c] += __shfl_xor(acc[c], off);
        }
        float v = acc[0];
#pragma unroll
        for (int c = 1; c < 8; ++c) v = (slot == c) ? acc[c] : v;
        v = v / (d + 1e-16f) + b2[slot];
        int b = batch[node];
        atomicAdd(&ps[b * 8 + slot], v);
        if (slot == 0) atomicAdd(&cs[b], 1.0f);
    }
    __syncthreads();
    for (int i = tid; i < 512; i += 256)
        if (ps[i] != 0.f) atomicAdd(&pool[i], ps[i]);
    if (tid < 64 && cs[tid] != 0.f) atomicAdd(&cnt[tid], cs[tid]);
}

__global__ __launch_bounds__(256) void final_kernel(const float* __restrict__ pool,
                                                    const float* __restrict__ cnt,
                                                    float* __restrict__ out, int B) {
    int idx = blockIdx.x * 256 + threadIdx.x;
    if (idx >= B * 8) return;
    out[idx] = pool[idx] / fmaxf(cnt[idx >> 3], 1.0f);
}

extern "C" void kernel_launch(void* const* d_in, const int* in_sizes, int n_in,
                              void* d_out, int out_size, void* d_ws, size_t ws_size,
                              hipStream_t stream) {
    const float* x   = (const float*)d_in[0];
    const int*   ei  = (const int*)d_in[1];
    const int*   bat = (const int*)d_in[2];
    const float* W1  = (const float*)d_in[3];
    const float* a1s = (const float*)d_in[4];
    const float* a1d = (const float*)d_in[5];
    const float* b1  = (const float*)d_in[6];
    const float* W2  = (const float*)d_in[7];
    const float* a2s = (const float*)d_in[8];
    const float* a2d = (const float*)d_in[9];
    const float* b2  = (const float*)d_in[10];
    float* out = (float*)d_out;

    const int N = in_sizes[0] / 128;
    const int E = in_sizes[1] / 2;
    const int B = out_size / 8;
    const int Etot = E + N;
    const int NB = (N + BIN_NODES - 1) / BIN_NODES;

    // ---- workspace layout (float slots) ----
    float* wsp = (float*)d_ws;
    __hip_bfloat16* xh1 = (__hip_bfloat16*)wsp;                      // 64N bf16 = 32N fl
    float* asrc1  = wsp + (size_t)N * 32;                            // 8N
    float* adst1  = asrc1 + (size_t)N * 8;                           // 8N
    __hip_bfloat16* xh2 = (__hip_bfloat16*)(adst1 + (size_t)N * 8);  // 8N bf16 = 4N fl
    float* asrc2  = adst1 + (size_t)N * 12;                          // N
    float* adst2  = asrc2 + (size_t)N;                               // N
    int*   rowptr = (int*)(adst2 + (size_t)N);                       // N+1 (+pad)
    int*   esrc   = rowptr + (size_t)N + 8;                          // Etot
    unsigned* binned = (unsigned*)(esrc + (size_t)Etot);             // NB*BIN_CAP
    // ---- zero-init region ----
    int*   cur    = (int*)(binned + (size_t)NB * BIN_CAP);           // NB
    float* pool   = (float*)(cur + NB);                              // 8B
    float* cnt    = pool + (size_t)B * 8;                            // B
    size_t zbytes = ((size_t)NB + 9 * (size_t)B) * 4;
    hipMemsetAsync(cur, 0, zbytes, stream);

    dim3 blk(256);
    gemm1_att_kernel<<<dim3((N + 31) / 32), blk, 0, stream>>>(x, W1, a1s, a1d, xh1, asrc1, adst1, N);
    binB_kernel<<<dim3((Etot + 256 * EPT - 1) / (256 * EPT)), blk, 0, stream>>>(ei, cur, binned, E, Etot, NB);
    binC_kernel<<<dim3(NB), blk, 0, stream>>>(cur, binned, rowptr, esrc, N, Etot, NB);
    agg1_fused_kernel<<<dim3((N + 3) / 4), blk, 0, stream>>>(rowptr, esrc, asrc1, adst1,
                                                             xh1, b1, W2, a2s, a2d,
                                                             xh2, asrc2, adst2, N);
    agg2_pool_kernel<<<dim3((N + 31) / 32), blk, 0, stream>>>(rowptr, esrc, asrc2, adst2,
                                                              xh2, b2, bat, pool, cnt, N, B);
    final_kernel<<<dim3((B * 8 + 255) / 256), blk, 0, stream>>>(pool, cnt, out, B);
}

// Round 7
// 185.435 us; speedup vs baseline: 24.5903x; 1.1265x over previous
//
#include <hip/hip_runtime.h>
#include <hip/hip_bf16.h>

#define BIN_SHIFT 8                  // 256 nodes per bin
#define BIN_NODES 256
#define BIN_CAP   8192
#define EPT       32                 // edges per thread in binB

typedef float v2f __attribute__((ext_vector_type(2)));

__device__ __forceinline__ float leaky02(float a) { return fmaxf(a, 0.2f * a); }
__device__ __forceinline__ unsigned short f2bf(float f) {
    __hip_bfloat16 h = __float2bfloat16(f);
    return *(unsigned short*)&h;
}
__device__ __forceinline__ float bflo(unsigned u) { return __uint_as_float(u << 16); }
__device__ __forceinline__ float bfhi(unsigned u) { return __uint_as_float(u & 0xffff0000u); }
__device__ __forceinline__ v2f bf2(unsigned u) {
    v2f r; r.x = __uint_as_float(u << 16); r.y = __uint_as_float(u & 0xffff0000u); return r;
}

// ---------- layer 1: x[N,128] @ W1[128,64] -> xh1(bf16) + att scalars ----------
__global__ __launch_bounds__(256) void gemm1_att_kernel(const float* __restrict__ x,
                                                        const float* __restrict__ W,
                                                        const float* __restrict__ a1s,
                                                        const float* __restrict__ a1d,
                                                        __hip_bfloat16* __restrict__ xh,
                                                        float* __restrict__ asrc,
                                                        float* __restrict__ adst, int N) {
    __shared__ float ws[128 * 64];
    __shared__ float xs[32][132];
    int tid = threadIdx.x;
    for (int i = tid; i < 2048; i += 256) ((float4*)ws)[i] = ((const float4*)W)[i];
    int row0 = blockIdx.x * 32;
    for (int i = tid; i < 32 * 32; i += 256) {
        int r = i >> 5, c4 = i & 31;
        int row = row0 + r;
        float4 v = make_float4(0.f, 0.f, 0.f, 0.f);
        if (row < N) v = ((const float4*)x)[row * 32 + c4];
        float* p = &xs[r][c4 * 4];
        p[0] = v.x; p[1] = v.y; p[2] = v.z; p[3] = v.w;
    }
    __syncthreads();
    int tc = tid & 15, tr = tid >> 4;
    float acc[2][4] = {};
#pragma unroll 4
    for (int k = 0; k < 128; ++k) {
        float a0 = xs[tr * 2][k];
        float a1 = xs[tr * 2 + 1][k];
        float4 b = *(const float4*)&ws[k * 64 + tc * 4];
        acc[0][0] += a0 * b.x; acc[0][1] += a0 * b.y; acc[0][2] += a0 * b.z; acc[0][3] += a0 * b.w;
        acc[1][0] += a1 * b.x; acc[1][1] += a1 * b.y; acc[1][2] += a1 * b.z; acc[1][3] += a1 * b.w;
    }
    float4 sv = ((const float4*)a1s)[tc];
    float4 dv = ((const float4*)a1d)[tc];
    int head = tc >> 1;
#pragma unroll
    for (int r = 0; r < 2; ++r) {
        int row = row0 + tr * 2 + r;
        if (row < N) {
            uint2 o;
            o.x = (unsigned)f2bf(acc[r][0]) | ((unsigned)f2bf(acc[r][1]) << 16);
            o.y = (unsigned)f2bf(acc[r][2]) | ((unsigned)f2bf(acc[r][3]) << 16);
            *(uint2*)(xh + (size_t)row * 64 + tc * 4) = o;
        }
        float sp = acc[r][0] * sv.x + acc[r][1] * sv.y + acc[r][2] * sv.z + acc[r][3] * sv.w;
        float dp = acc[r][0] * dv.x + acc[r][1] * dv.y + acc[r][2] * dv.z + acc[r][3] * dv.w;
        sp += __shfl_xor(sp, 1);
        dp += __shfl_xor(dp, 1);
        if (!(tc & 1) && row < N) {
            asrc[row * 8 + head] = sp;
            adst[row * 8 + head] = dp;
        }
    }
}

// ---------- binB: bin edges by dst>>8 into fixed-capacity buckets ----------
__global__ __launch_bounds__(256) void binB_kernel(const int* __restrict__ ei,
                                                   int* __restrict__ cur,
                                                   unsigned* __restrict__ binned,
                                                   int E, int Etot, int NB) {
    __shared__ int bcnt[512];
    int tid = threadIdx.x;
    for (int i = tid; i < 512; i += 256) bcnt[i] = 0;
    __syncthreads();
    long long base = (long long)blockIdx.x * 256 * EPT;
#pragma unroll 4
    for (int i = 0; i < EPT; ++i) {
        long long e = base + i * 256 + tid;
        if (e < Etot) {
            int dst = (e < E) ? ei[E + e] : (int)(e - E);
            atomicAdd(&bcnt[dst >> BIN_SHIFT], 1);
        }
    }
    __syncthreads();
    for (int b = tid; b < NB; b += 256) {
        int c = bcnt[b];
        bcnt[b] = c ? atomicAdd(&cur[b], c) : 0;
    }
    __syncthreads();
#pragma unroll 4
    for (int i = 0; i < EPT; ++i) {
        long long e = base + i * 256 + tid;
        if (e < Etot) {
            int src, dst;
            if (e < E) { src = ei[e]; dst = ei[E + e]; }
            else       { src = dst = (int)(e - E); }
            int bin = dst >> BIN_SHIFT;
            int p = atomicAdd(&bcnt[bin], 1);
            if (p < BIN_CAP)
                binned[(size_t)bin * BIN_CAP + p] = ((unsigned)(dst & (BIN_NODES - 1)) << 24) | (unsigned)src;
        }
    }
}

// ---------- binC: per-bin -> rowptr + in-bin scatter to esrc ----------
__global__ __launch_bounds__(256) void binC_kernel(const int* __restrict__ cur,
                                                   const unsigned* __restrict__ binned,
                                                   int* __restrict__ rowptr,
                                                   int* __restrict__ esrc,
                                                   int N, int Etot, int NB) {
    int bin = blockIdx.x;
    int tid = threadIdx.x;
    __shared__ int psum[256];
    __shared__ int sc[256];
    __shared__ int ndc[256];
    int s = 0;
    for (int i = tid; i < bin; i += 256) s += cur[i];
    psum[tid] = s;
    __syncthreads();
    for (int off = 128; off > 0; off >>= 1) {
        if (tid < off) psum[tid] += psum[tid + off];
        __syncthreads();
    }
    int bbase = psum[0];
    int cnt = cur[bin];
    ndc[tid] = 0;
    __syncthreads();
    const unsigned* bp = binned + (size_t)bin * BIN_CAP;
    for (int i = tid; i < cnt; i += 256)
        atomicAdd(&ndc[bp[i] >> 24], 1);
    __syncthreads();
    int v = ndc[tid];
    sc[tid] = v;
    __syncthreads();
    for (int off = 1; off < 256; off <<= 1) {
        int t = (tid >= off) ? sc[tid - off] : 0;
        __syncthreads();
        sc[tid] += t;
        __syncthreads();
    }
    int excl = sc[tid] - v;
    int node = bin * BIN_NODES + tid;
    if (node < N) rowptr[node] = bbase + excl;
    if (bin == NB - 1 && tid == 0) rowptr[N] = Etot;
    ndc[tid] = excl;
    __syncthreads();
    for (int i = tid; i < cnt; i += 256) {
        unsigned w = bp[i];
        int p = atomicAdd(&ndc[w >> 24], 1);
        esrc[bbase + p] = (int)(w & 0xFFFFFFu);
    }
}

// ---------- layer-1 aggregate + bias + ELU -> h1 (bf16, natural feature order) ----------
// one wave per node; lane = slot*8 + h; 2 edges per lane per iteration
__global__ __launch_bounds__(256) void agg1_kernel(const int* __restrict__ rowptr,
                                                   const int* __restrict__ esrc,
                                                   const float* __restrict__ asrc,
                                                   const float* __restrict__ adst,
                                                   const __hip_bfloat16* __restrict__ xh,
                                                   const float* __restrict__ b1,
                                                   __hip_bfloat16* __restrict__ h1, int N) {
    int node = blockIdx.x * 4 + (threadIdx.x >> 6);
    if (node >= N) return;
    int lane = threadIdx.x & 63;
    unsigned slot = (unsigned)(lane >> 3), h = (unsigned)(lane & 7);
    float adh = adst[(unsigned)node * 8u + h];
    unsigned start = (unsigned)rowptr[node];
    int len = rowptr[node + 1] - (int)start;
    const uint4* xh4 = (const uint4*)xh;
    float d = 0.f;
    v2f acc0 = {0.f, 0.f}, acc1 = {0.f, 0.f}, acc2 = {0.f, 0.f}, acc3 = {0.f, 0.f};
    for (int kb = 0; kb < len; kb += 16) {
        int k0 = kb + (int)slot, k1 = k0 + 8;
        bool ok0 = k0 < len, ok1 = k1 < len;
        unsigned s0 = ok0 ? (unsigned)esrc[start + k0] : 0u;
        unsigned s1 = ok1 ? (unsigned)esrc[start + k1] : 0u;
        float a0 = ok0 ? asrc[s0 * 8u + h] : -1e30f;
        float a1 = ok1 ? asrc[s1 * 8u + h] : -1e30f;
        uint4 u0 = xh4[s0 * 8u + h];
        uint4 u1 = xh4[s1 * 8u + h];
        float p0 = __expf(leaky02(a0 + adh));
        float p1 = __expf(leaky02(a1 + adh));
        d += p0 + p1;
        acc0 += bf2(u0.x) * p0; acc1 += bf2(u0.y) * p0;
        acc2 += bf2(u0.z) * p0; acc3 += bf2(u0.w) * p0;
        acc0 += bf2(u1.x) * p1; acc1 += bf2(u1.y) * p1;
        acc2 += bf2(u1.z) * p1; acc3 += bf2(u1.w) * p1;
    }
    // reduce over the 8 slot-lanes (lane bits 3..5)
#pragma unroll
    for (int off = 8; off < 64; off <<= 1) {
        d += __shfl_xor(d, off);
        acc0.x += __shfl_xor(acc0.x, off); acc0.y += __shfl_xor(acc0.y, off);
        acc1.x += __shfl_xor(acc1.x, off); acc1.y += __shfl_xor(acc1.y, off);
        acc2.x += __shfl_xor(acc2.x, off); acc2.y += __shfl_xor(acc2.y, off);
        acc3.x += __shfl_xor(acc3.x, off); acc3.y += __shfl_xor(acc3.y, off);
    }
    float vals[8] = {acc0.x, acc0.y, acc1.x, acc1.y, acc2.x, acc2.y, acc3.x, acc3.y};
    float hv = vals[0];
#pragma unroll
    for (int c = 1; c < 8; ++c) hv = ((int)slot == c) ? vals[c] : hv;
    int f = (int)(h * 8u + slot);
    hv = hv / (d + 1e-16f) + b1[f];
    hv = hv > 0.f ? hv : __expf(hv) - 1.0f;          // ELU
    // permute so lane stores feature f' = lane (contiguous 2B stores)
    float hvp = __shfl(hv, ((lane & 7) << 3) | (lane >> 3));
    h1[(unsigned)node * 64u + (unsigned)lane] = __float2bfloat16(hvp);
}

// ---------- layer-2 GEMM: h1[N,64](bf16) @ W2[64,8] + att2 scalars ----------
__global__ __launch_bounds__(256) void gemm2h_kernel(const __hip_bfloat16* __restrict__ h1,
                                                     const float* __restrict__ W2,
                                                     const float* __restrict__ a2s,
                                                     const float* __restrict__ a2d,
                                                     __hip_bfloat16* __restrict__ xh2,
                                                     float* __restrict__ asrc2,
                                                     float* __restrict__ adst2, int N) {
    __shared__ float w2s[512];
    __shared__ float aa[16];
    int tid = threadIdx.x;
    for (int i = tid; i < 512; i += 256) w2s[i] = W2[i];
    if (tid < 8) aa[tid] = a2s[tid];
    else if (tid < 16) aa[tid] = a2d[tid - 8];
    __syncthreads();
    unsigned n = blockIdx.x * 256u + (unsigned)tid;
    if (n >= (unsigned)N) return;
    const uint4* hp = (const uint4*)h1 + n * 8u;
    float q[8] = {};
#pragma unroll
    for (int j = 0; j < 8; ++j) {
        uint4 u = hp[j];
        float hv[8] = {bflo(u.x), bfhi(u.x), bflo(u.y), bfhi(u.y),
                       bflo(u.z), bfhi(u.z), bflo(u.w), bfhi(u.w)};
#pragma unroll
        for (int e = 0; e < 8; ++e) {
            int f = j * 8 + e;
            float4 wa = *(const float4*)&w2s[f * 8];
            float4 wb = *(const float4*)&w2s[f * 8 + 4];
            q[0] += hv[e] * wa.x; q[1] += hv[e] * wa.y;
            q[2] += hv[e] * wa.z; q[3] += hv[e] * wa.w;
            q[4] += hv[e] * wb.x; q[5] += hv[e] * wb.y;
            q[6] += hv[e] * wb.z; q[7] += hv[e] * wb.w;
        }
    }
    uint4 o;
    o.x = (unsigned)f2bf(q[0]) | ((unsigned)f2bf(q[1]) << 16);
    o.y = (unsigned)f2bf(q[2]) | ((unsigned)f2bf(q[3]) << 16);
    o.z = (unsigned)f2bf(q[4]) | ((unsigned)f2bf(q[5]) << 16);
    o.w = (unsigned)f2bf(q[6]) | ((unsigned)f2bf(q[7]) << 16);
    *((uint4*)xh2 + n) = o;
    float s2 = 0.f, d2 = 0.f;
#pragma unroll
    for (int c = 0; c < 8; ++c) { s2 += q[c] * aa[c]; d2 += q[c] * aa[8 + c]; }
    asrc2[n] = s2;
    adst2[n] = d2;
}

// ---------- layer-2 aggregate + bias + fused mean-pool stage ----------
__global__ __launch_bounds__(256) void agg2_pool_kernel(const int* __restrict__ rowptr,
                                                        const int* __restrict__ esrc,
                                                        const float* __restrict__ asrc2,
                                                        const float* __restrict__ adst2,
                                                        const __hip_bfloat16* __restrict__ xh2,
                                                        const float* __restrict__ b2,
                                                        const int* __restrict__ batch,
                                                        float* __restrict__ pool,
                                                        float* __restrict__ cnt, int N, int B) {
    __shared__ float ps[64 * 8];
    __shared__ float cs[64];
    int tid = threadIdx.x;
    for (int i = tid; i < 512; i += 256) ps[i] = 0.f;
    if (tid < 64) cs[tid] = 0.f;
    __syncthreads();
    int node = blockIdx.x * 32 + (tid >> 3);
    int slot = tid & 7;
    if (node < N) {
        float adh = adst2[node];
        unsigned start = (unsigned)rowptr[node];
        int len = rowptr[node + 1] - (int)start;
        const uint4* x4 = (const uint4*)xh2;
        float d = 0.f;
        v2f acc0 = {0.f, 0.f}, acc1 = {0.f, 0.f}, acc2 = {0.f, 0.f}, acc3 = {0.f, 0.f};
        for (int kb = 0; kb < len; kb += 16) {
            int k0 = kb + slot, k1 = k0 + 8;
            bool ok0 = k0 < len, ok1 = k1 < len;
            unsigned s0 = ok0 ? (unsigned)esrc[start + k0] : 0u;
            unsigned s1 = ok1 ? (unsigned)esrc[start + k1] : 0u;
            float a0 = ok0 ? asrc2[s0] : -1e30f;
            float a1 = ok1 ? asrc2[s1] : -1e30f;
            uint4 u0 = x4[s0];
            uint4 u1 = x4[s1];
            float p0 = __expf(leaky02(a0 + adh));
            float p1 = __expf(leaky02(a1 + adh));
            d += p0 + p1;
            acc0 += bf2(u0.x) * p0; acc1 += bf2(u0.y) * p0;
            acc2 += bf2(u0.z) * p0; acc3 += bf2(u0.w) * p0;
            acc0 += bf2(u1.x) * p1; acc1 += bf2(u1.y) * p1;
            acc2 += bf2(u1.z) * p1; acc3 += bf2(u1.w) * p1;
        }
#pragma unroll
        for (int off = 1; off < 8; off <<= 1) {
            d += __shfl_xor(d, off);
            acc0.x += __shfl_xor(acc0.x, off); acc0.y += __shfl_xor(acc0.y, off);
            acc1.x += __shfl_xor(acc1.x, off); acc1.y += __shfl_xor(acc1.y, off);
            acc2.x += __shfl_xor(acc2.x, off); acc2.y += __shfl_xor(acc2.y, off);
            acc3.x += __shfl_xor(acc3.x, off); acc3.y += __shfl_xor(acc3.y, off);
        }
        float vals[8] = {acc0.x, acc0.y, acc1.x, acc1.y, acc2.x, acc2.y, acc3.x, acc3.y};
        float v = vals[0];
#pragma unroll
        for (int c = 1; c < 8; ++c) v = (slot == c) ? vals[c] : v;
        v = v / (d + 1e-16f) + b2[slot];
        int b = batch[node];
        atomicAdd(&ps[b * 8 + slot], v);
        if (slot == 0) atomicAdd(&cs[b], 1.0f);
    }
    __syncthreads();
    for (int i = tid; i < 512; i += 256)
        if (ps[i] != 0.f) atomicAdd(&pool[i], ps[i]);
    if (tid < 64 && cs[tid] != 0.f) atomicAdd(&cnt[tid], cs[tid]);
}

__global__ __launch_bounds__(256) void final_kernel(const float* __restrict__ pool,
                                                    const float* __restrict__ cnt,
                                                    float* __restrict__ out, int B) {
    int idx = blockIdx.x * 256 + threadIdx.x;
    if (idx >= B * 8) return;
    out[idx] = pool[idx] / fmaxf(cnt[idx >> 3], 1.0f);
}

extern "C" void kernel_launch(void* const* d_in, const int* in_sizes, int n_in,
                              void* d_out, int out_size, void* d_ws, size_t ws_size,
                              hipStream_t stream) {
    const float* x   = (const float*)d_in[0];
    const int*   ei  = (const int*)d_in[1];
    const int*   bat = (const int*)d_in[2];
    const float* W1  = (const float*)d_in[3];
    const float* a1s = (const float*)d_in[4];
    const float* a1d = (const float*)d_in[5];
    const float* b1  = (const float*)d_in[6];
    const float* W2  = (const float*)d_in[7];
    const float* a2s = (const float*)d_in[8];
    const float* a2d = (const float*)d_in[9];
    const float* b2  = (const float*)d_in[10];
    float* out = (float*)d_out;

    const int N = in_sizes[0] / 128;
    const int E = in_sizes[1] / 2;
    const int B = out_size / 8;
    const int Etot = E + N;
    const int NB = (N + BIN_NODES - 1) / BIN_NODES;

    // ---- workspace layout (float slots) ----
    float* wsp = (float*)d_ws;
    __hip_bfloat16* xh1 = (__hip_bfloat16*)wsp;                       // 64N bf16 = 32N fl
    float* asrc1  = wsp + (size_t)N * 32;                             // 8N
    float* adst1  = asrc1 + (size_t)N * 8;                            // 8N
    __hip_bfloat16* h1 = (__hip_bfloat16*)(adst1 + (size_t)N * 8);    // 64N bf16 = 32N fl
    __hip_bfloat16* xh2 = (__hip_bfloat16*)(adst1 + (size_t)N * 40);  // 8N bf16 = 4N fl
    float* asrc2  = adst1 + (size_t)N * 44;                           // N
    float* adst2  = asrc2 + (size_t)N;                                // N
    int*   rowptr = (int*)(adst2 + (size_t)N);                        // N+1 (+pad)
    int*   esrc   = rowptr + (size_t)N + 8;                           // Etot
    unsigned* binned = (unsigned*)(esrc + (size_t)Etot);              // NB*BIN_CAP
    // ---- zero-init region ----
    int*   cur    = (int*)(binned + (size_t)NB * BIN_CAP);            // NB
    float* pool   = (float*)(cur + NB);                               // 8B
    float* cnt    = pool + (size_t)B * 8;                             // B
    size_t zbytes = ((size_t)NB + 9 * (size_t)B) * 4;
    hipMemsetAsync(cur, 0, zbytes, stream);

    dim3 blk(256);
    gemm1_att_kernel<<<dim3((N + 31) / 32), blk, 0, stream>>>(x, W1, a1s, a1d, xh1, asrc1, adst1, N);
    binB_kernel<<<dim3((Etot + 256 * EPT - 1) / (256 * EPT)), blk, 0, stream>>>(ei, cur, binned, E, Etot, NB);
    binC_kernel<<<dim3(NB), blk, 0, stream>>>(cur, binned, rowptr, esrc, N, Etot, NB);
    agg1_kernel<<<dim3((N + 3) / 4), blk, 0, stream>>>(rowptr, esrc, asrc1, adst1, xh1, b1, h1, N);
    gemm2h_kernel<<<dim3((N + 255) / 256), blk, 0, stream>>>(h1, W2, a2s, a2d, xh2, asrc2, adst2, N);
    agg2_pool_kernel<<<dim3((N + 31) / 32), blk, 0, stream>>>(rowptr, esrc, asrc2, adst2,
                                                              xh2, b2, bat, pool, cnt, N, B);
    final_kernel<<<dim3((B * 8 + 255) / 256), blk, 0, stream>>>(pool, cnt, out, B);
}

// Round 8
// 185.153 us; speedup vs baseline: 24.6278x; 1.0015x over previous
//
#include <hip/hip_runtime.h>
#include <hip/hip_bf16.h>

#define BIN_SHIFT 8                  // 256 nodes per bin
#define BIN_NODES 256
#define BIN_CAP   8192
#define EPT       32                 // edges per thread in binB

typedef float v2f __attribute__((ext_vector_type(2)));

__device__ __forceinline__ float leaky02(float a) { return fmaxf(a, 0.2f * a); }
__device__ __forceinline__ unsigned short f2bf(float f) {
    __hip_bfloat16 h = __float2bfloat16(f);
    return *(unsigned short*)&h;
}
__device__ __forceinline__ v2f bf2(unsigned u) {
    v2f r; r.x = __uint_as_float(u << 16); r.y = __uint_as_float(u & 0xffff0000u); return r;
}

// ---------- layer 1: x[N,128] @ W1[128,64] -> xh1(bf16) + att scalars ----------
// 64-row tile, 512 threads: LDS 32KB(W)+33.8KB(x) -> 2 blocks/CU, 16 waves/CU
__global__ __launch_bounds__(512) void gemm1_att_kernel(const float* __restrict__ x,
                                                        const float* __restrict__ W,
                                                        const float* __restrict__ a1s,
                                                        const float* __restrict__ a1d,
                                                        __hip_bfloat16* __restrict__ xh,
                                                        float* __restrict__ asrc,
                                                        float* __restrict__ adst, int N) {
    __shared__ float ws[128 * 64];
    __shared__ float xs[64][132];
    int tid = threadIdx.x;
    for (int i = tid; i < 2048; i += 512) ((float4*)ws)[i] = ((const float4*)W)[i];
    int row0 = blockIdx.x * 64;
    for (int i = tid; i < 64 * 32; i += 512) {
        int r = i >> 5, c4 = i & 31;
        int row = row0 + r;
        float4 v = make_float4(0.f, 0.f, 0.f, 0.f);
        if (row < N) v = ((const float4*)x)[row * 32 + c4];
        float* p = &xs[r][c4 * 4];
        p[0] = v.x; p[1] = v.y; p[2] = v.z; p[3] = v.w;
    }
    __syncthreads();
    int tc = tid & 15, tr = tid >> 4;      // tr 0..31 -> rows 2tr,2tr+1; cols 4tc..
    float acc[2][4] = {};
#pragma unroll 4
    for (int k = 0; k < 128; ++k) {
        float a0 = xs[tr * 2][k];
        float a1 = xs[tr * 2 + 1][k];
        float4 b = *(const float4*)&ws[k * 64 + tc * 4];
        acc[0][0] += a0 * b.x; acc[0][1] += a0 * b.y; acc[0][2] += a0 * b.z; acc[0][3] += a0 * b.w;
        acc[1][0] += a1 * b.x; acc[1][1] += a1 * b.y; acc[1][2] += a1 * b.z; acc[1][3] += a1 * b.w;
    }
    float4 sv = ((const float4*)a1s)[tc];
    float4 dv = ((const float4*)a1d)[tc];
    int head = tc >> 1;
#pragma unroll
    for (int r = 0; r < 2; ++r) {
        int row = row0 + tr * 2 + r;
        if (row < N) {
            uint2 o;
            o.x = (unsigned)f2bf(acc[r][0]) | ((unsigned)f2bf(acc[r][1]) << 16);
            o.y = (unsigned)f2bf(acc[r][2]) | ((unsigned)f2bf(acc[r][3]) << 16);
            *(uint2*)(xh + (size_t)row * 64 + tc * 4) = o;
        }
        float sp = acc[r][0] * sv.x + acc[r][1] * sv.y + acc[r][2] * sv.z + acc[r][3] * sv.w;
        float dp = acc[r][0] * dv.x + acc[r][1] * dv.y + acc[r][2] * dv.z + acc[r][3] * dv.w;
        sp += __shfl_xor(sp, 1);
        dp += __shfl_xor(dp, 1);
        if (!(tc & 1) && row < N) {
            asrc[row * 8 + head] = sp;
            adst[row * 8 + head] = dp;
        }
    }
}

// ---------- binB: bin edges by dst>>8 into fixed-capacity buckets ----------
__global__ __launch_bounds__(256) void binB_kernel(const int* __restrict__ ei,
                                                   int* __restrict__ cur,
                                                   unsigned* __restrict__ binned,
                                                   int E, int Etot, int NB) {
    __shared__ int bcnt[512];
    int tid = threadIdx.x;
    for (int i = tid; i < 512; i += 256) bcnt[i] = 0;
    __syncthreads();
    long long base = (long long)blockIdx.x * 256 * EPT;
#pragma unroll 4
    for (int i = 0; i < EPT; ++i) {
        long long e = base + i * 256 + tid;
        if (e < Etot) {
            int dst = (e < E) ? ei[E + e] : (int)(e - E);
            atomicAdd(&bcnt[dst >> BIN_SHIFT], 1);
        }
    }
    __syncthreads();
    for (int b = tid; b < NB; b += 256) {
        int c = bcnt[b];
        bcnt[b] = c ? atomicAdd(&cur[b], c) : 0;
    }
    __syncthreads();
#pragma unroll 4
    for (int i = 0; i < EPT; ++i) {
        long long e = base + i * 256 + tid;
        if (e < Etot) {
            int src, dst;
            if (e < E) { src = ei[e]; dst = ei[E + e]; }
            else       { src = dst = (int)(e - E); }
            int bin = dst >> BIN_SHIFT;
            int p = atomicAdd(&bcnt[bin], 1);
            if (p < BIN_CAP)
                binned[(size_t)bin * BIN_CAP + p] = ((unsigned)(dst & (BIN_NODES - 1)) << 24) | (unsigned)src;
        }
    }
}

// ---------- binC: per-bin -> rowptr + in-bin scatter to esrc ----------
__global__ __launch_bounds__(256) void binC_kernel(const int* __restrict__ cur,
                                                   const unsigned* __restrict__ binned,
                                                   int* __restrict__ rowptr,
                                                   int* __restrict__ esrc,
                                                   int N, int Etot, int NB) {
    int bin = blockIdx.x;
    int tid = threadIdx.x;
    __shared__ int psum[256];
    __shared__ int sc[256];
    __shared__ int ndc[256];
    int s = 0;
    for (int i = tid; i < bin; i += 256) s += cur[i];
    psum[tid] = s;
    __syncthreads();
    for (int off = 128; off > 0; off >>= 1) {
        if (tid < off) psum[tid] += psum[tid + off];
        __syncthreads();
    }
    int bbase = psum[0];
    int cnt = cur[bin];
    ndc[tid] = 0;
    __syncthreads();
    const unsigned* bp = binned + (size_t)bin * BIN_CAP;
    for (int i = tid; i < cnt; i += 256)
        atomicAdd(&ndc[bp[i] >> 24], 1);
    __syncthreads();
    int v = ndc[tid];
    sc[tid] = v;
    __syncthreads();
    for (int off = 1; off < 256; off <<= 1) {
        int t = (tid >= off) ? sc[tid - off] : 0;
        __syncthreads();
        sc[tid] += t;
        __syncthreads();
    }
    int excl = sc[tid] - v;
    int node = bin * BIN_NODES + tid;
    if (node < N) rowptr[node] = bbase + excl;
    if (bin == NB - 1 && tid == 0) rowptr[N] = Etot;
    ndc[tid] = excl;
    __syncthreads();
    for (int i = tid; i < cnt; i += 256) {
        unsigned w = bp[i];
        int p = atomicAdd(&ndc[w >> 24], 1);
        esrc[bbase + p] = (int)(w & 0xFFFFFFu);
    }
}

// ---------- fused: layer-1 aggregate + bias + ELU + layer-2 GEMV + att2 scalars ----------
// lane-local softmax: lane = (ni, h); wave = 8 nodes x 8 heads; no cross-lane reduce in loop
__global__ __launch_bounds__(256) void agg1_fused_kernel(const int* __restrict__ rowptr,
                                                         const int* __restrict__ esrc,
                                                         const float* __restrict__ asrc,
                                                         const float* __restrict__ adst,
                                                         const __hip_bfloat16* __restrict__ xh,
                                                         const float* __restrict__ b1,
                                                         const float* __restrict__ W2,
                                                         const float* __restrict__ a2s,
                                                         const float* __restrict__ a2d,
                                                         __hip_bfloat16* __restrict__ xh2,
                                                         float* __restrict__ asrc2,
                                                         float* __restrict__ adst2, int N) {
    __shared__ float w2s[64 * 9];   // pitch 9: h-groups land on distinct bank sets
    __shared__ float aa[16];
    int tid = threadIdx.x;
    for (int i = tid; i < 512; i += 256) w2s[(i >> 3) * 9 + (i & 7)] = W2[i];
    if (tid < 8) aa[tid] = a2s[tid];
    else if (tid < 16) aa[tid] = a2d[tid - 8];
    __syncthreads();
    int lane = tid & 63;
    int ni = lane >> 3, h = lane & 7;
    int node = blockIdx.x * 32 + (tid >> 6) * 8 + ni;
    bool valid = node < N;
    unsigned start = 0; int len = 0; float adh = 0.f;
    if (valid) {
        start = (unsigned)rowptr[node];
        len = rowptr[node + 1] - (int)start;
        adh = adst[(unsigned)node * 8u + (unsigned)h];
    }
    int ml = len;
    ml = max(ml, __shfl_xor(ml, 8));
    ml = max(ml, __shfl_xor(ml, 16));
    ml = max(ml, __shfl_xor(ml, 32));
    const uint4* xh4 = (const uint4*)xh;
    float d = 0.f;
    v2f acc0 = {0.f, 0.f}, acc1 = {0.f, 0.f}, acc2 = {0.f, 0.f}, acc3 = {0.f, 0.f};
    for (int k = 0; k < ml; ++k) {
        bool ok = k < len;
        unsigned s = ok ? (unsigned)esrc[start + k] : 0u;
        float av = ok ? asrc[s * 8u + (unsigned)h] : -1e30f;
        uint4 u = xh4[s * 8u + (unsigned)h];
        float p = __expf(leaky02(av + adh));   // masked lanes: exp(-2e29)=0
        d += p;
        acc0 += bf2(u.x) * p; acc1 += bf2(u.y) * p;
        acc2 += bf2(u.z) * p; acc3 += bf2(u.w) * p;
    }
    float inv = 1.0f / (d + 1e-16f);
    float hv[8] = {acc0.x, acc0.y, acc1.x, acc1.y, acc2.x, acc2.y, acc3.x, acc3.y};
    const float4* bp4 = (const float4*)(b1 + h * 8);
    float4 bA = bp4[0], bB = bp4[1];
    float bb[8] = {bA.x, bA.y, bA.z, bA.w, bB.x, bB.y, bB.z, bB.w};
    float q[8] = {};
#pragma unroll
    for (int c = 0; c < 8; ++c) {
        float v = hv[c] * inv + bb[c];
        v = v > 0.f ? v : __expf(v) - 1.0f;          // ELU
        const float* wr = &w2s[(h * 8 + c) * 9];
#pragma unroll
        for (int j = 0; j < 8; ++j) q[j] += v * wr[j];
    }
    // reduce q over the 8 h-lanes (bits 0..2)
#pragma unroll
    for (int off = 1; off < 8; off <<= 1)
#pragma unroll
        for (int j = 0; j < 8; ++j) q[j] += __shfl_xor(q[j], off);
    if (valid && h == 0) {
        uint4 o;
        o.x = (unsigned)f2bf(q[0]) | ((unsigned)f2bf(q[1]) << 16);
        o.y = (unsigned)f2bf(q[2]) | ((unsigned)f2bf(q[3]) << 16);
        o.z = (unsigned)f2bf(q[4]) | ((unsigned)f2bf(q[5]) << 16);
        o.w = (unsigned)f2bf(q[6]) | ((unsigned)f2bf(q[7]) << 16);
        *((uint4*)xh2 + node) = o;
        float s2 = 0.f, d2 = 0.f;
#pragma unroll
        for (int c = 0; c < 8; ++c) { s2 += q[c] * aa[c]; d2 += q[c] * aa[8 + c]; }
        asrc2[node] = s2;
        adst2[node] = d2;
    }
}

// ---------- layer-2 aggregate + bias + fused mean-pool ----------
// lane = (ni, cp); wave = 16 nodes x 4 channel-pairs; lane-local softmax
__global__ __launch_bounds__(256) void agg2_pool_kernel(const int* __restrict__ rowptr,
                                                        const int* __restrict__ esrc,
                                                        const float* __restrict__ asrc2,
                                                        const float* __restrict__ adst2,
                                                        const __hip_bfloat16* __restrict__ xh2,
                                                        const float* __restrict__ b2,
                                                        const int* __restrict__ batch,
                                                        float* __restrict__ pool,
                                                        float* __restrict__ cnt, int N, int B) {
    __shared__ float ps[64 * 8];
    __shared__ float cs[64];
    int tid = threadIdx.x;
    for (int i = tid; i < 512; i += 256) ps[i] = 0.f;
    if (tid < 64) cs[tid] = 0.f;
    __syncthreads();
    int lane = tid & 63;
    int ni = lane >> 2, cp = lane & 3;
    int node = blockIdx.x * 64 + (tid >> 6) * 16 + ni;
    bool valid = node < N;
    unsigned start = 0; int len = 0; float adh = 0.f;
    if (valid) {
        start = (unsigned)rowptr[node];
        len = rowptr[node + 1] - (int)start;
        adh = adst2[node];
    }
    int ml = len;
    ml = max(ml, __shfl_xor(ml, 4));
    ml = max(ml, __shfl_xor(ml, 8));
    ml = max(ml, __shfl_xor(ml, 16));
    ml = max(ml, __shfl_xor(ml, 32));
    const unsigned* x2 = (const unsigned*)xh2;
    float d = 0.f;
    v2f acc = {0.f, 0.f};
    for (int k = 0; k < ml; ++k) {
        bool ok = k < len;
        unsigned s = ok ? (unsigned)esrc[start + k] : 0u;
        float av = ok ? asrc2[s] : -1e30f;
        unsigned u = x2[s * 4u + (unsigned)cp];
        float p = __expf(leaky02(av + adh));
        d += p;
        acc += bf2(u) * p;
    }
    if (valid) {
        float inv = 1.0f / (d + 1e-16f);
        int b = batch[node];
        float vx = acc.x * inv + b2[cp * 2];
        float vy = acc.y * inv + b2[cp * 2 + 1];
        atomicAdd(&ps[b * 8 + cp * 2], vx);
        atomicAdd(&ps[b * 8 + cp * 2 + 1], vy);
        if (cp == 0) atomicAdd(&cs[b], 1.0f);
    }
    __syncthreads();
    for (int i = tid; i < 512; i += 256)
        if (ps[i] != 0.f) atomicAdd(&pool[i], ps[i]);
    if (tid < 64 && cs[tid] != 0.f) atomicAdd(&cnt[tid], cs[tid]);
}

__global__ __launch_bounds__(256) void final_kernel(const float* __restrict__ pool,
                                                    const float* __restrict__ cnt,
                                                    float* __restrict__ out, int B) {
    int idx = blockIdx.x * 256 + threadIdx.x;
    if (idx >= B * 8) return;
    out[idx] = pool[idx] / fmaxf(cnt[idx >> 3], 1.0f);
}

extern "C" void kernel_launch(void* const* d_in, const int* in_sizes, int n_in,
                              void* d_out, int out_size, void* d_ws, size_t ws_size,
                              hipStream_t stream) {
    const float* x   = (const float*)d_in[0];
    const int*   ei  = (const int*)d_in[1];
    const int*   bat = (const int*)d_in[2];
    const float* W1  = (const float*)d_in[3];
    const float* a1s = (const float*)d_in[4];
    const float* a1d = (const float*)d_in[5];
    const float* b1  = (const float*)d_in[6];
    const float* W2  = (const float*)d_in[7];
    const float* a2s = (const float*)d_in[8];
    const float* a2d = (const float*)d_in[9];
    const float* b2  = (const float*)d_in[10];
    float* out = (float*)d_out;

    const int N = in_sizes[0] / 128;
    const int E = in_sizes[1] / 2;
    const int B = out_size / 8;
    const int Etot = E + N;
    const int NB = (N + BIN_NODES - 1) / BIN_NODES;

    // ---- workspace layout (float slots) ----
    float* wsp = (float*)d_ws;
    __hip_bfloat16* xh1 = (__hip_bfloat16*)wsp;                       // 64N bf16 = 32N fl
    float* asrc1  = wsp + (size_t)N * 32;                             // 8N
    float* adst1  = asrc1 + (size_t)N * 8;                            // 8N
    __hip_bfloat16* xh2 = (__hip_bfloat16*)(adst1 + (size_t)N * 8);   // 8N bf16 = 4N fl
    float* asrc2  = adst1 + (size_t)N * 12;                           // N
    float* adst2  = asrc2 + (size_t)N;                                // N
    int*   rowptr = (int*)(adst2 + (size_t)N);                        // N+1 (+pad)
    int*   esrc   = rowptr + (size_t)N + 8;                           // Etot
    unsigned* binned = (unsigned*)(esrc + (size_t)Etot);              // NB*BIN_CAP
    // ---- zero-init region ----
    int*   cur    = (int*)(binned + (size_t)NB * BIN_CAP);            // NB
    float* pool   = (float*)(cur + NB);                               // 8B
    float* cnt    = pool + (size_t)B * 8;                             // B
    size_t zbytes = ((size_t)NB + 9 * (size_t)B) * 4;
    hipMemsetAsync(cur, 0, zbytes, stream);

    gemm1_att_kernel<<<dim3((N + 63) / 64), dim3(512), 0, stream>>>(x, W1, a1s, a1d, xh1, asrc1, adst1, N);
    binB_kernel<<<dim3((Etot + 256 * EPT - 1) / (256 * EPT)), dim3(256), 0, stream>>>(ei, cur, binned, E, Etot, NB);
    binC_kernel<<<dim3(NB), dim3(256), 0, stream>>>(cur, binned, rowptr, esrc, N, Etot, NB);
    agg1_fused_kernel<<<dim3((N + 31) / 32), dim3(256), 0, stream>>>(rowptr, esrc, asrc1, adst1,
                                                                     xh1, b1, W2, a2s, a2d,
                                                                     xh2, asrc2, adst2, N);
    agg2_pool_kernel<<<dim3((N + 63) / 64), dim3(256), 0, stream>>>(rowptr, esrc, asrc2, adst2,
                                                                    xh2, b2, bat, pool, cnt, N, B);
    final_kernel<<<dim3((B * 8 + 255) / 256), dim3(256), 0, stream>>>(pool, cnt, out, B);
}

// Round 9
// 180.527 us; speedup vs baseline: 25.2588x; 1.0256x over previous
//
#include <hip/hip_runtime.h>
#include <hip/hip_bf16.h>

#define BIN_SHIFT 8                  // 256 nodes per bin
#define BIN_NODES 256
#define BIN_CAP   8192
#define EPT       16                 // edges per thread in binB

typedef float v2f __attribute__((ext_vector_type(2)));

__device__ __forceinline__ float leaky02(float a) { return fmaxf(a, 0.2f * a); }
__device__ __forceinline__ unsigned short f2bf(float f) {
    __hip_bfloat16 h = __float2bfloat16(f);
    return *(unsigned short*)&h;
}
__device__ __forceinline__ float bflo(unsigned u) { return __uint_as_float(u << 16); }
__device__ __forceinline__ float bfhi(unsigned u) { return __uint_as_float(u & 0xffff0000u); }
__device__ __forceinline__ v2f bf2(unsigned u) {
    v2f r; r.x = __uint_as_float(u << 16); r.y = __uint_as_float(u & 0xffff0000u); return r;
}

// ---------- layer 1: x[N,128] @ W1[128,64] -> xh1(bf16) + att scalars ----------
__global__ __launch_bounds__(512) void gemm1_att_kernel(const float* __restrict__ x,
                                                        const float* __restrict__ W,
                                                        const float* __restrict__ a1s,
                                                        const float* __restrict__ a1d,
                                                        __hip_bfloat16* __restrict__ xh,
                                                        float* __restrict__ asrc,
                                                        float* __restrict__ adst, int N) {
    __shared__ float ws[128 * 64];
    __shared__ float xs[64][132];
    int tid = threadIdx.x;
    for (int i = tid; i < 2048; i += 512) ((float4*)ws)[i] = ((const float4*)W)[i];
    int row0 = blockIdx.x * 64;
    for (int i = tid; i < 64 * 32; i += 512) {
        int r = i >> 5, c4 = i & 31;
        int row = row0 + r;
        float4 v = make_float4(0.f, 0.f, 0.f, 0.f);
        if (row < N) v = ((const float4*)x)[row * 32 + c4];
        float* p = &xs[r][c4 * 4];
        p[0] = v.x; p[1] = v.y; p[2] = v.z; p[3] = v.w;
    }
    __syncthreads();
    int tc = tid & 15, tr = tid >> 4;
    float acc[2][4] = {};
#pragma unroll 4
    for (int k = 0; k < 128; ++k) {
        float a0 = xs[tr * 2][k];
        float a1 = xs[tr * 2 + 1][k];
        float4 b = *(const float4*)&ws[k * 64 + tc * 4];
        acc[0][0] += a0 * b.x; acc[0][1] += a0 * b.y; acc[0][2] += a0 * b.z; acc[0][3] += a0 * b.w;
        acc[1][0] += a1 * b.x; acc[1][1] += a1 * b.y; acc[1][2] += a1 * b.z; acc[1][3] += a1 * b.w;
    }
    float4 sv = ((const float4*)a1s)[tc];
    float4 dv = ((const float4*)a1d)[tc];
    int head = tc >> 1;
#pragma unroll
    for (int r = 0; r < 2; ++r) {
        int row = row0 + tr * 2 + r;
        if (row < N) {
            uint2 o;
            o.x = (unsigned)f2bf(acc[r][0]) | ((unsigned)f2bf(acc[r][1]) << 16);
            o.y = (unsigned)f2bf(acc[r][2]) | ((unsigned)f2bf(acc[r][3]) << 16);
            *(uint2*)(xh + (size_t)row * 64 + tc * 4) = o;
        }
        float sp = acc[r][0] * sv.x + acc[r][1] * sv.y + acc[r][2] * sv.z + acc[r][3] * sv.w;
        float dp = acc[r][0] * dv.x + acc[r][1] * dv.y + acc[r][2] * dv.z + acc[r][3] * dv.w;
        sp += __shfl_xor(sp, 1);
        dp += __shfl_xor(dp, 1);
        if (!(tc & 1) && row < N) {
            asrc[row * 8 + head] = sp;
            adst[row * 8 + head] = dp;
        }
    }
}

// ---------- binB: bin edges by dst>>8 into fixed-capacity buckets ----------
__global__ __launch_bounds__(256) void binB_kernel(const int* __restrict__ ei,
                                                   int* __restrict__ cur,
                                                   unsigned* __restrict__ binned,
                                                   int E, int Etot, int NB) {
    __shared__ int bcnt[512];
    int tid = threadIdx.x;
    for (int i = tid; i < 512; i += 256) bcnt[i] = 0;
    __syncthreads();
    long long base = (long long)blockIdx.x * 256 * EPT;
#pragma unroll 4
    for (int i = 0; i < EPT; ++i) {
        long long e = base + i * 256 + tid;
        if (e < Etot) {
            int dst = (e < E) ? ei[E + e] : (int)(e - E);
            atomicAdd(&bcnt[dst >> BIN_SHIFT], 1);
        }
    }
    __syncthreads();
    for (int b = tid; b < NB; b += 256) {
        int c = bcnt[b];
        bcnt[b] = c ? atomicAdd(&cur[b], c) : 0;
    }
    __syncthreads();
#pragma unroll 4
    for (int i = 0; i < EPT; ++i) {
        long long e = base + i * 256 + tid;
        if (e < Etot) {
            int src, dst;
            if (e < E) { src = ei[e]; dst = ei[E + e]; }
            else       { src = dst = (int)(e - E); }
            int bin = dst >> BIN_SHIFT;
            int p = atomicAdd(&bcnt[bin], 1);
            if (p < BIN_CAP)
                binned[(size_t)bin * BIN_CAP + p] = ((unsigned)(dst & (BIN_NODES - 1)) << 24) | (unsigned)src;
        }
    }
}

// ---------- binC: per-bin -> rowptr + in-bin scatter to esrc ----------
__global__ __launch_bounds__(256) void binC_kernel(const int* __restrict__ cur,
                                                   const unsigned* __restrict__ binned,
                                                   int* __restrict__ rowptr,
                                                   int* __restrict__ esrc,
                                                   int N, int Etot, int NB) {
    int bin = blockIdx.x;
    int tid = threadIdx.x;
    __shared__ int psum[256];
    __shared__ int sc[256];
    __shared__ int ndc[256];
    int s = 0;
    for (int i = tid; i < bin; i += 256) s += cur[i];
    psum[tid] = s;
    __syncthreads();
    for (int off = 128; off > 0; off >>= 1) {
        if (tid < off) psum[tid] += psum[tid + off];
        __syncthreads();
    }
    int bbase = psum[0];
    int cnt = cur[bin];
    ndc[tid] = 0;
    __syncthreads();
    const unsigned* bp = binned + (size_t)bin * BIN_CAP;
    for (int i = tid; i < cnt; i += 256)
        atomicAdd(&ndc[bp[i] >> 24], 1);
    __syncthreads();
    int v = ndc[tid];
    sc[tid] = v;
    __syncthreads();
    for (int off = 1; off < 256; off <<= 1) {
        int t = (tid >= off) ? sc[tid - off] : 0;
        __syncthreads();
        sc[tid] += t;
        __syncthreads();
    }
    int excl = sc[tid] - v;
    int node = bin * BIN_NODES + tid;
    if (node < N) rowptr[node] = bbase + excl;
    if (bin == NB - 1 && tid == 0) rowptr[N] = Etot;
    ndc[tid] = excl;
    __syncthreads();
    for (int i = tid; i < cnt; i += 256) {
        unsigned w = bp[i];
        int p = atomicAdd(&ndc[w >> 24], 1);
        esrc[bbase + p] = (int)(w & 0xFFFFFFu);
    }
}

// ---------- layer-1 aggregate + bias + ELU -> h1 (bf16) ----------
// one wave per node; lane = slot*8 + h; 4 edges per lane per iteration (12 load chains)
__global__ __launch_bounds__(256) void agg1_kernel(const int* __restrict__ rowptr,
                                                   const int* __restrict__ esrc,
                                                   const float* __restrict__ asrc,
                                                   const float* __restrict__ adst,
                                                   const __hip_bfloat16* __restrict__ xh,
                                                   const float* __restrict__ b1,
                                                   __hip_bfloat16* __restrict__ h1, int N) {
    int node = blockIdx.x * 4 + (threadIdx.x >> 6);
    if (node >= N) return;
    int lane = threadIdx.x & 63;
    unsigned slot = (unsigned)(lane >> 3), h = (unsigned)(lane & 7);
    float adh = adst[(unsigned)node * 8u + h];
    unsigned start = (unsigned)rowptr[node];
    int len = rowptr[node + 1] - (int)start;
    const uint4* xh4 = (const uint4*)xh;
    float d = 0.f;
    v2f acc0 = {0.f, 0.f}, acc1 = {0.f, 0.f}, acc2 = {0.f, 0.f}, acc3 = {0.f, 0.f};
    for (int kb = 0; kb < len; kb += 32) {
        int k0 = kb + (int)slot;
        bool ok0 = k0 < len, ok1 = k0 + 8 < len, ok2 = k0 + 16 < len, ok3 = k0 + 24 < len;
        unsigned s0 = ok0 ? (unsigned)esrc[start + k0] : 0u;
        unsigned s1 = ok1 ? (unsigned)esrc[start + k0 + 8] : 0u;
        unsigned s2 = ok2 ? (unsigned)esrc[start + k0 + 16] : 0u;
        unsigned s3 = ok3 ? (unsigned)esrc[start + k0 + 24] : 0u;
        float a0 = ok0 ? asrc[s0 * 8u + h] : -1e30f;
        float a1 = ok1 ? asrc[s1 * 8u + h] : -1e30f;
        float a2 = ok2 ? asrc[s2 * 8u + h] : -1e30f;
        float a3 = ok3 ? asrc[s3 * 8u + h] : -1e30f;
        uint4 u0 = xh4[s0 * 8u + h];
        uint4 u1 = xh4[s1 * 8u + h];
        uint4 u2 = xh4[s2 * 8u + h];
        uint4 u3 = xh4[s3 * 8u + h];
        float p0 = __expf(leaky02(a0 + adh));
        float p1 = __expf(leaky02(a1 + adh));
        float p2 = __expf(leaky02(a2 + adh));
        float p3 = __expf(leaky02(a3 + adh));
        d += (p0 + p1) + (p2 + p3);
        acc0 += bf2(u0.x) * p0; acc1 += bf2(u0.y) * p0;
        acc2 += bf2(u0.z) * p0; acc3 += bf2(u0.w) * p0;
        acc0 += bf2(u1.x) * p1; acc1 += bf2(u1.y) * p1;
        acc2 += bf2(u1.z) * p1; acc3 += bf2(u1.w) * p1;
        acc0 += bf2(u2.x) * p2; acc1 += bf2(u2.y) * p2;
        acc2 += bf2(u2.z) * p2; acc3 += bf2(u2.w) * p2;
        acc0 += bf2(u3.x) * p3; acc1 += bf2(u3.y) * p3;
        acc2 += bf2(u3.z) * p3; acc3 += bf2(u3.w) * p3;
    }
    // reduce over the 8 slot-lanes (lane bits 3..5)
#pragma unroll
    for (int off = 8; off < 64; off <<= 1) {
        d += __shfl_xor(d, off);
        acc0.x += __shfl_xor(acc0.x, off); acc0.y += __shfl_xor(acc0.y, off);
        acc1.x += __shfl_xor(acc1.x, off); acc1.y += __shfl_xor(acc1.y, off);
        acc2.x += __shfl_xor(acc2.x, off); acc2.y += __shfl_xor(acc2.y, off);
        acc3.x += __shfl_xor(acc3.x, off); acc3.y += __shfl_xor(acc3.y, off);
    }
    float vals[8] = {acc0.x, acc0.y, acc1.x, acc1.y, acc2.x, acc2.y, acc3.x, acc3.y};
    float hv = vals[0];
#pragma unroll
    for (int c = 1; c < 8; ++c) hv = ((int)slot == c) ? vals[c] : hv;
    int f = (int)(h * 8u + slot);
    hv = hv / (d + 1e-16f) + b1[f];
    hv = hv > 0.f ? hv : __expf(hv) - 1.0f;          // ELU
    // permute so lane stores feature f' = lane (contiguous 2B stores)
    float hvp = __shfl(hv, ((lane & 7) << 3) | (lane >> 3));
    h1[(unsigned)node * 64u + (unsigned)lane] = __float2bfloat16(hvp);
}

// ---------- layer-2 GEMM: h1[N,64](bf16) @ W2[64,8] + att2 scalars ----------
__global__ __launch_bounds__(256) void gemm2h_kernel(const __hip_bfloat16* __restrict__ h1,
                                                     const float* __restrict__ W2,
                                                     const float* __restrict__ a2s,
                                                     const float* __restrict__ a2d,
                                                     __hip_bfloat16* __restrict__ xh2,
                                                     float* __restrict__ asrc2,
                                                     float* __restrict__ adst2, int N) {
    __shared__ float w2s[512];
    __shared__ float aa[16];
    int tid = threadIdx.x;
    for (int i = tid; i < 512; i += 256) w2s[i] = W2[i];
    if (tid < 8) aa[tid] = a2s[tid];
    else if (tid < 16) aa[tid] = a2d[tid - 8];
    __syncthreads();
    unsigned n = blockIdx.x * 256u + (unsigned)tid;
    if (n >= (unsigned)N) return;
    const uint4* hp = (const uint4*)h1 + n * 8u;
    float q[8] = {};
#pragma unroll
    for (int j = 0; j < 8; ++j) {
        uint4 u = hp[j];
        float hv[8] = {bflo(u.x), bfhi(u.x), bflo(u.y), bfhi(u.y),
                       bflo(u.z), bfhi(u.z), bflo(u.w), bfhi(u.w)};
#pragma unroll
        for (int e = 0; e < 8; ++e) {
            int f = j * 8 + e;
            float4 wa = *(const float4*)&w2s[f * 8];
            float4 wb = *(const float4*)&w2s[f * 8 + 4];
            q[0] += hv[e] * wa.x; q[1] += hv[e] * wa.y;
            q[2] += hv[e] * wa.z; q[3] += hv[e] * wa.w;
            q[4] += hv[e] * wb.x; q[5] += hv[e] * wb.y;
            q[6] += hv[e] * wb.z; q[7] += hv[e] * wb.w;
        }
    }
    uint4 o;
    o.x = (unsigned)f2bf(q[0]) | ((unsigned)f2bf(q[1]) << 16);
    o.y = (unsigned)f2bf(q[2]) | ((unsigned)f2bf(q[3]) << 16);
    o.z = (unsigned)f2bf(q[4]) | ((unsigned)f2bf(q[5]) << 16);
    o.w = (unsigned)f2bf(q[6]) | ((unsigned)f2bf(q[7]) << 16);
    *((uint4*)xh2 + n) = o;
    float s2 = 0.f, d2 = 0.f;
#pragma unroll
    for (int c = 0; c < 8; ++c) { s2 += q[c] * aa[c]; d2 += q[c] * aa[8 + c]; }
    asrc2[n] = s2;
    adst2[n] = d2;
}

// ---------- layer-2 aggregate + bias + fused mean-pool (slot form, 4-edge unroll) ----------
__global__ __launch_bounds__(256) void agg2_pool_kernel(const int* __restrict__ rowptr,
                                                        const int* __restrict__ esrc,
                                                        const float* __restrict__ asrc2,
                                                        const float* __restrict__ adst2,
                                                        const __hip_bfloat16* __restrict__ xh2,
                                                        const float* __restrict__ b2,
                                                        const int* __restrict__ batch,
                                                        float* __restrict__ pool,
                                                        float* __restrict__ cnt, int N, int B) {
    __shared__ float ps[64 * 8];
    __shared__ float cs[64];
    int tid = threadIdx.x;
    for (int i = tid; i < 512; i += 256) ps[i] = 0.f;
    if (tid < 64) cs[tid] = 0.f;
    __syncthreads();
    int node = blockIdx.x * 32 + (tid >> 3);
    int slot = tid & 7;
    if (node < N) {
        float adh = adst2[node];
        unsigned start = (unsigned)rowptr[node];
        int len = rowptr[node + 1] - (int)start;
        const uint4* x4 = (const uint4*)xh2;
        float d = 0.f;
        v2f acc0 = {0.f, 0.f}, acc1 = {0.f, 0.f}, acc2 = {0.f, 0.f}, acc3 = {0.f, 0.f};
        for (int kb = 0; kb < len; kb += 32) {
            int k0 = kb + slot;
            bool ok0 = k0 < len, ok1 = k0 + 8 < len, ok2 = k0 + 16 < len, ok3 = k0 + 24 < len;
            unsigned s0 = ok0 ? (unsigned)esrc[start + k0] : 0u;
            unsigned s1 = ok1 ? (unsigned)esrc[start + k0 + 8] : 0u;
            unsigned s2 = ok2 ? (unsigned)esrc[start + k0 + 16] : 0u;
            unsigned s3 = ok3 ? (unsigned)esrc[start + k0 + 24] : 0u;
            float a0 = ok0 ? asrc2[s0] : -1e30f;
            float a1 = ok1 ? asrc2[s1] : -1e30f;
            float a2 = ok2 ? asrc2[s2] : -1e30f;
            float a3 = ok3 ? asrc2[s3] : -1e30f;
            uint4 u0 = x4[s0];
            uint4 u1 = x4[s1];
            uint4 u2 = x4[s2];
            uint4 u3 = x4[s3];
            float p0 = __expf(leaky02(a0 + adh));
            float p1 = __expf(leaky02(a1 + adh));
            float p2 = __expf(leaky02(a2 + adh));
            float p3 = __expf(leaky02(a3 + adh));
            d += (p0 + p1) + (p2 + p3);
            acc0 += bf2(u0.x) * p0; acc1 += bf2(u0.y) * p0;
            acc2 += bf2(u0.z) * p0; acc3 += bf2(u0.w) * p0;
            acc0 += bf2(u1.x) * p1; acc1 += bf2(u1.y) * p1;
            acc2 += bf2(u1.z) * p1; acc3 += bf2(u1.w) * p1;
            acc0 += bf2(u2.x) * p2; acc1 += bf2(u2.y) * p2;
            acc2 += bf2(u2.z) * p2; acc3 += bf2(u2.w) * p2;
            acc0 += bf2(u3.x) * p3; acc1 += bf2(u3.y) * p3;
            acc2 += bf2(u3.z) * p3; acc3 += bf2(u3.w) * p3;
        }
#pragma unroll
        for (int off = 1; off < 8; off <<= 1) {
            d += __shfl_xor(d, off);
            acc0.x += __shfl_xor(acc0.x, off); acc0.y += __shfl_xor(acc0.y, off);
            acc1.x += __shfl_xor(acc1.x, off); acc1.y += __shfl_xor(acc1.y, off);
            acc2.x += __shfl_xor(acc2.x, off); acc2.y += __shfl_xor(acc2.y, off);
            acc3.x += __shfl_xor(acc3.x, off); acc3.y += __shfl_xor(acc3.y, off);
        }
        float vals[8] = {acc0.x, acc0.y, acc1.x, acc1.y, acc2.x, acc2.y, acc3.x, acc3.y};
        float v = vals[0];
#pragma unroll
        for (int c = 1; c < 8; ++c) v = (slot == c) ? vals[c] : v;
        v = v / (d + 1e-16f) + b2[slot];
        int b = batch[node];
        atomicAdd(&ps[b * 8 + slot], v);
        if (slot == 0) atomicAdd(&cs[b], 1.0f);
    }
    __syncthreads();
    for (int i = tid; i < 512; i += 256)
        if (ps[i] != 0.f) atomicAdd(&pool[i], ps[i]);
    if (tid < 64 && cs[tid] != 0.f) atomicAdd(&cnt[tid], cs[tid]);
}

__global__ __launch_bounds__(256) void final_kernel(const float* __restrict__ pool,
                                                    const float* __restrict__ cnt,
                                                    float* __restrict__ out, int B) {
    int idx = blockIdx.x * 256 + threadIdx.x;
    if (idx >= B * 8) return;
    out[idx] = pool[idx] / fmaxf(cnt[idx >> 3], 1.0f);
}

extern "C" void kernel_launch(void* const* d_in, const int* in_sizes, int n_in,
                              void* d_out, int out_size, void* d_ws, size_t ws_size,
                              hipStream_t stream) {
    const float* x   = (const float*)d_in[0];
    const int*   ei  = (const int*)d_in[1];
    const int*   bat = (const int*)d_in[2];
    const float* W1  = (const float*)d_in[3];
    const float* a1s = (const float*)d_in[4];
    const float* a1d = (const float*)d_in[5];
    const float* b1  = (const float*)d_in[6];
    const float* W2  = (const float*)d_in[7];
    const float* a2s = (const float*)d_in[8];
    const float* a2d = (const float*)d_in[9];
    const float* b2  = (const float*)d_in[10];
    float* out = (float*)d_out;

    const int N = in_sizes[0] / 128;
    const int E = in_sizes[1] / 2;
    const int B = out_size / 8;
    const int Etot = E + N;
    const int NB = (N + BIN_NODES - 1) / BIN_NODES;

    // ---- workspace layout (float slots) ----
    float* wsp = (float*)d_ws;
    __hip_bfloat16* xh1 = (__hip_bfloat16*)wsp;                       // 64N bf16 = 32N fl
    float* asrc1  = wsp + (size_t)N * 32;                             // 8N
    float* adst1  = asrc1 + (size_t)N * 8;                            // 8N
    __hip_bfloat16* h1 = (__hip_bfloat16*)(adst1 + (size_t)N * 8);    // 64N bf16 = 32N fl
    __hip_bfloat16* xh2 = (__hip_bfloat16*)(adst1 + (size_t)N * 40);  // 8N bf16 = 4N fl
    float* asrc2  = adst1 + (size_t)N * 44;                           // N
    float* adst2  = asrc2 + (size_t)N;                                // N
    int*   rowptr = (int*)(adst2 + (size_t)N);                        // N+1 (+pad)
    int*   esrc   = rowptr + (size_t)N + 8;                           // Etot
    unsigned* binned = (unsigned*)(esrc + (size_t)Etot);              // NB*BIN_CAP
    // ---- zero-init region ----
    int*   cur    = (int*)(binned + (size_t)NB * BIN_CAP);            // NB
    float* pool   = (float*)(cur + NB);                               // 8B
    float* cnt    = pool + (size_t)B * 8;                             // B
    size_t zbytes = ((size_t)NB + 9 * (size_t)B) * 4;
    hipMemsetAsync(cur, 0, zbytes, stream);

    gemm1_att_kernel<<<dim3((N + 63) / 64), dim3(512), 0, stream>>>(x, W1, a1s, a1d, xh1, asrc1, adst1, N);
    binB_kernel<<<dim3((Etot + 256 * EPT - 1) / (256 * EPT)), dim3(256), 0, stream>>>(ei, cur, binned, E, Etot, NB);
    binC_kernel<<<dim3(NB), dim3(256), 0, stream>>>(cur, binned, rowptr, esrc, N, Etot, NB);
    agg1_kernel<<<dim3((N + 3) / 4), dim3(256), 0, stream>>>(rowptr, esrc, asrc1, adst1, xh1, b1, h1, N);
    gemm2h_kernel<<<dim3((N + 255) / 256), dim3(256), 0, stream>>>(h1, W2, a2s, a2d, xh2, asrc2, adst2, N);
    agg2_pool_kernel<<<dim3((N + 31) / 32), dim3(256), 0, stream>>>(rowptr, esrc, asrc2, adst2,
                                                                    xh2, b2, bat, pool, cnt, N, B);
    final_kernel<<<dim3((B * 8 + 255) / 256), dim3(256), 0, stream>>>(pool, cnt, out, B);
}